// Round 6
// baseline (736.995 us; speedup 1.0000x reference)
//
#include <hip/hip_runtime.h>
#include <hip/hip_bf16.h>

// AttentiveGraph: B=4, N=10000, E=160000, C=F=128, 3 iterations.
// R6 = R5 with the double-lq*8 bug fixed (gemm_tile_packed callers passed
// row base + lq*8 while the helper also added lq*8 -> wrong A-frags for
// lq>0 lanes in the lg@Wl GEMM; absmax 0.127).
// R5 design kept: (a) CSR build via node-window partitioning + LDS counters
// (zero scattered global atomics); (b) edge gather split into channel
// halves, XCD=(batch,half) -> 2.56MB slab fits 4MB L2; (c) packed
// {lg bf16 | sa fp16} u32 edge outputs.

#define BATCH 4
#define NNODE 10000
#define NEDGE 160000
#define TWOE  (2*NEDGE)
#define MROWS (BATCH*NNODE)   // 40000
#define NWIN  32              // CSR windows per batch
#define WINSZ 313             // ceil(10000/32)

typedef unsigned short u16;
typedef unsigned int   u32;
typedef __attribute__((ext_vector_type(8))) short bf16x8_t;
typedef __attribute__((ext_vector_type(4))) float f32x4_t;

__device__ __forceinline__ float b2f(u16 h){ return __uint_as_float(((u32)h) << 16); }
__device__ __forceinline__ u16 f2bf(float f){
  u32 u = __float_as_uint(f);
  return (u16)((u + 0x7fffu + ((u >> 16) & 1u)) >> 16);   // RNE
}
__device__ __forceinline__ float fast_tanh(float x){
  float e = __expf(2.0f * x);
  return fmaf(-2.0f, __builtin_amdgcn_rcpf(e + 1.0f), 1.0f);
}

// ---------------- storage dtype probe (fp32 vs bf16 storage) ------------------
__global__ void detect_dtype(const u32* __restrict__ objw, int* __restrict__ flag){
  __shared__ int zc, hc;
  if (threadIdx.x == 0){ zc = 0; hc = 0; }
  __syncthreads();
  int z = 0, h = 0;
  for (int i = threadIdx.x; i < 1024; i += 256){
    u32 lo = objw[i] & 0xffffu;
    if (lo == 0) z++;
    if (((lo >> 7) & 0xffu) >= 160u) h++;
  }
  atomicAdd(&zc, z); atomicAdd(&hc, h);
  __syncthreads();
  if (threadIdx.x == 0) *flag = (hc > 0 || zc > 512) ? 1 : 0;   // 1 = fp32 storage
}

// Wt[m][c*128+k] = W_m[k*128+c]; tail block converts biases.
__global__ void prep_weights(const void* __restrict__ Wo, const void* __restrict__ Wa,
                             const void* __restrict__ Wla, const void* __restrict__ Wl,
                             const void* __restrict__ ab, const void* __restrict__ sb,
                             const int* __restrict__ flag, u16* __restrict__ Wt,
                             float* __restrict__ biasf){
  int idx = blockIdx.x * 256 + threadIdx.x;
  bool f = (*flag != 0);
  if (idx < 65536){
    int m = idx >> 14, k = (idx >> 7) & 127, c = idx & 127;
    const void* src = (m == 0) ? Wo : (m == 1) ? Wa : (m == 2) ? Wla : Wl;
    u16 h = f ? f2bf(((const float*)src)[k * 128 + c]) : ((const u16*)src)[k * 128 + c];
    Wt[m * 16384 + c * 128 + k] = h;
  } else {
    int t = idx - 65536;
    const void* src = (t < 128) ? sb : ab;
    int i = t & 127;
    biasf[t] = f ? ((const float*)src)[i] : b2f(((const u16*)src)[i]);
  }
}

// ---------------- CSR build: window partition, LDS counters -------------------
__device__ __forceinline__ void win_of(int blk, int& b, int& w0, int& w1){
  int xcd = blk & 7;
  b = xcd >> 1;
  int sub = ((blk >> 3) << 1) | (xcd & 1);     // 0..31
  w0 = sub * WINSZ;
  w1 = w0 + WINSZ; if (w1 > NNODE) w1 = NNODE;
}

__global__ void __launch_bounds__(256) count_edges(const int* __restrict__ conn,
                                                   int* __restrict__ counts){
  int b, w0, w1; win_of(blockIdx.x, b, w0, w1);
  __shared__ int cnt[WINSZ];
  for (int t = threadIdx.x; t < WINSZ; t += 256) cnt[t] = 0;
  __syncthreads();
  const int2* cp = (const int2*)conn + (size_t)b * NEDGE;
  for (int e = threadIdx.x; e < NEDGE; e += 256){
    int2 c = cp[e];
    if (c.x >= w0 && c.x < w1) atomicAdd(&cnt[c.x - w0], 1);
    if (c.y >= w0 && c.y < w1) atomicAdd(&cnt[c.y - w0], 1);
  }
  __syncthreads();
  for (int t = threadIdx.x; t < w1 - w0; t += 256) counts[b * NNODE + w0 + t] = cnt[t];
}

// scanA: per 256-node chunk local exclusive scan + chunk totals. 160 blocks.
__global__ void scanA(const int* __restrict__ counts, int* __restrict__ row_start,
                      int* __restrict__ bsum){
  int b = blockIdx.x / 40, j = blockIdx.x % 40;
  int n = j * 256 + threadIdx.x;
  __shared__ int buf[256];
  int v = (n < NNODE) ? counts[b * NNODE + n] : 0;
  buf[threadIdx.x] = v;
  __syncthreads();
  for (int off = 1; off < 256; off <<= 1){
    int x = (threadIdx.x >= (unsigned)off) ? buf[threadIdx.x - off] : 0;
    __syncthreads();
    buf[threadIdx.x] += x;
    __syncthreads();
  }
  int incl = buf[threadIdx.x];
  if (n < NNODE) row_start[b * (NNODE + 1) + n] = incl - v;
  if (threadIdx.x == 255) bsum[blockIdx.x] = incl;
}

__global__ void scanB(const int* __restrict__ bsum, int* __restrict__ boff,
                      int* __restrict__ row_start){
  __shared__ int s[160];
  if (threadIdx.x < 160) s[threadIdx.x] = bsum[threadIdx.x];
  __syncthreads();
  if (threadIdx.x < 160){
    int b = threadIdx.x / 40, j = threadIdx.x % 40;
    int off = 0;
    for (int q = b * 40; q < b * 40 + j; q++) off += s[q];
    boff[threadIdx.x] = off;
  }
  if (threadIdx.x < BATCH) row_start[threadIdx.x * (NNODE + 1) + NNODE] = TWOE;
}

__global__ void scanC(int* __restrict__ row_start, const int* __restrict__ boff){
  int b = blockIdx.x / 40, j = blockIdx.x % 40;
  int n = j * 256 + threadIdx.x;
  if (n < NNODE) row_start[b * (NNODE + 1) + n] += boff[blockIdx.x];
}

__global__ void __launch_bounds__(256) fill_edges(const int* __restrict__ conn,
    const int* __restrict__ row_start, int* __restrict__ edge_dst){
  int b, w0, w1; win_of(blockIdx.x, b, w0, w1);
  __shared__ int cur[WINSZ];
  for (int t = threadIdx.x; t < w1 - w0; t += 256)
    cur[t] = row_start[b * (NNODE + 1) + w0 + t];
  __syncthreads();
  const int2* cp = (const int2*)conn + (size_t)b * NEDGE;
  int* edb = edge_dst + (size_t)b * TWOE;
  for (int e = threadIdx.x; e < NEDGE; e += 256){
    int2 c = cp[e];
    if (c.x >= w0 && c.x < w1){ int p = atomicAdd(&cur[c.x - w0], 1); edb[p] = c.y; }
    if (c.y >= w0 && c.y < w1){ int p = atomicAdd(&cur[c.y - w0], 1); edb[p] = c.x; }
  }
}

// ---------------- MFMA helpers (wave = 16 rows x 128 cols) --------------------
__device__ __forceinline__ void gemm_tile(const u16* __restrict__ arow,
    const u16* __restrict__ wt, int lm, int lq, f32x4_t acc[8]){
  #pragma unroll
  for (int ks = 0; ks < 4; ks++){
    bf16x8_t a = *(const bf16x8_t*)(arow + ks * 32);
    #pragma unroll
    for (int nb = 0; nb < 8; nb++){
      bf16x8_t bfr = *(const bf16x8_t*)(wt + (nb * 16 + lm) * 128 + ks * 32 + lq * 8);
      acc[nb] = __builtin_amdgcn_mfma_f32_16x16x32_bf16(a, bfr, acc[nb], 0, 0, 0);
    }
  }
}

// A-frag from packed lgsa (lg = low u16 of each u32). Lrow = row base ONLY
// (helper adds lq*8 itself — R5 bug was adding it in both places).
__device__ __forceinline__ void gemm_tile_packed(const u32* __restrict__ Lrow,
    const u16* __restrict__ wt, int lm, int lq, f32x4_t acc[8]){
  #pragma unroll
  for (int ks = 0; ks < 4; ks++){
    uint4 wa = *(const uint4*)(Lrow + ks * 32 + lq * 8);
    uint4 wb = *(const uint4*)(Lrow + ks * 32 + lq * 8 + 4);
    bf16x8_t a;
    a[0] = (short)wa.x; a[1] = (short)wa.y; a[2] = (short)wa.z; a[3] = (short)wa.w;
    a[4] = (short)wb.x; a[5] = (short)wb.y; a[6] = (short)wb.z; a[7] = (short)wb.w;
    #pragma unroll
    for (int nb = 0; nb < 8; nb++){
      bf16x8_t bfr = *(const bf16x8_t*)(wt + (nb * 16 + lm) * 128 + ks * 32 + lq * 8);
      acc[nb] = __builtin_amdgcn_mfma_f32_16x16x32_bf16(a, bfr, acc[nb], 0, 0, 0);
    }
  }
}

// phase 2: states tile (LDS, A-layout) -> aW fp32 + EL slots in gat halves
__device__ __forceinline__ void phase2_awlaw(const u16* __restrict__ ldsrow,
    const u16* __restrict__ Wt, const float* __restrict__ biasf,
    int lm, int lq, int r0, float* __restrict__ awsa,
    u32* __restrict__ gat0, u32* __restrict__ gat1){
  const u16* Wta  = Wt + 16384;
  const u16* Wtla = Wt + 32768;
  f32x4_t accA[8], accL[8];
  #pragma unroll
  for (int i = 0; i < 8; i++){ accA[i] = (f32x4_t){0.f,0.f,0.f,0.f}; accL[i] = (f32x4_t){0.f,0.f,0.f,0.f}; }
  #pragma unroll
  for (int ks = 0; ks < 4; ks++){
    bf16x8_t a = *(const bf16x8_t*)(ldsrow + ks * 32);
    #pragma unroll
    for (int nb = 0; nb < 8; nb++){
      bf16x8_t ba = *(const bf16x8_t*)(Wta  + (nb * 16 + lm) * 128 + ks * 32 + lq * 8);
      bf16x8_t bl = *(const bf16x8_t*)(Wtla + (nb * 16 + lm) * 128 + ks * 32 + lq * 8);
      accA[nb] = __builtin_amdgcn_mfma_f32_16x16x32_bf16(a, ba, accA[nb], 0, 0, 0);
      accL[nb] = __builtin_amdgcn_mfma_f32_16x16x32_bf16(a, bl, accL[nb], 0, 0, 0);
    }
  }
  #pragma unroll
  for (int nb = 0; nb < 8; nb++){
    int col = nb * 16 + lm;
    u16* gh = (u16*)((nb < 4) ? gat0 : gat1);
    float bb = biasf[128 + col];
    #pragma unroll
    for (int i = 0; i < 4; i++){
      int row = r0 + lq * 4 + i;
      awsa[(size_t)row * 128 + col] = accA[nb][i];
      gh[((size_t)row * 64 + (col & 63)) * 2] = f2bf(__expf(accL[nb][i] + bb));  // EL slot
    }
  }
}

// init: states = tanh(obj@Wo + b) from raw objects; then aW/EL.
__global__ void __launch_bounds__(256) fused_init(const void* __restrict__ obj_raw,
    const int* __restrict__ flag, const u16* __restrict__ Wt,
    const float* __restrict__ biasf, float* __restrict__ awsa,
    u32* __restrict__ gat0, u32* __restrict__ gat1){
  __shared__ u16 lds[4][16][136];
  const int lane = threadIdx.x & 63, wave = threadIdx.x >> 6;
  const int r0 = blockIdx.x * 64 + wave * 16;
  const int lm = lane & 15, lq = lane >> 4;
  f32x4_t acc[8];
  #pragma unroll
  for (int i = 0; i < 8; i++) acc[i] = (f32x4_t){0.f, 0.f, 0.f, 0.f};
  if (*flag){
    const float* arow = (const float*)obj_raw + (size_t)(r0 + lm) * 128 + lq * 8;
    #pragma unroll
    for (int ks = 0; ks < 4; ks++){
      float4 fa = *(const float4*)(arow + ks * 32);
      float4 fb = *(const float4*)(arow + ks * 32 + 4);
      bf16x8_t a;
      a[0] = (short)f2bf(fa.x); a[1] = (short)f2bf(fa.y);
      a[2] = (short)f2bf(fa.z); a[3] = (short)f2bf(fa.w);
      a[4] = (short)f2bf(fb.x); a[5] = (short)f2bf(fb.y);
      a[6] = (short)f2bf(fb.z); a[7] = (short)f2bf(fb.w);
      #pragma unroll
      for (int nb = 0; nb < 8; nb++){
        bf16x8_t bfr = *(const bf16x8_t*)(Wt + (nb * 16 + lm) * 128 + ks * 32 + lq * 8);
        acc[nb] = __builtin_amdgcn_mfma_f32_16x16x32_bf16(a, bfr, acc[nb], 0, 0, 0);
      }
    }
  } else {
    gemm_tile((const u16*)obj_raw + (size_t)(r0 + lm) * 128 + lq * 8, Wt, lm, lq, acc);
  }
  #pragma unroll
  for (int nb = 0; nb < 8; nb++){
    int col = nb * 16 + lm;
    u16* gh = (u16*)((nb < 4) ? gat0 : gat1);
    float bb = biasf[col];
    #pragma unroll
    for (int i = 0; i < 4; i++){
      int row = r0 + lq * 4 + i;
      u16 h = f2bf(fast_tanh(acc[nb][i] + bb));
      gh[((size_t)row * 64 + (col & 63)) * 2 + 1] = h;   // S slot
      lds[wave][lq * 4 + i][col] = h;
    }
  }
  __syncthreads();
  phase2_awlaw(&lds[wave][lm][lq * 8], Wt, biasf, lm, lq, r0, awsa, gat0, gat1);
}

// mid: states = tanh(sa + lg@Wl + b); then aW/EL for next iter.
__global__ void __launch_bounds__(256) fused_mid(const u32* __restrict__ lgsa,
    const u16* __restrict__ Wt, const float* __restrict__ biasf,
    float* __restrict__ awsa, u32* __restrict__ gat0, u32* __restrict__ gat1){
  __shared__ u16 lds[4][16][136];
  const int lane = threadIdx.x & 63, wave = threadIdx.x >> 6;
  const int r0 = blockIdx.x * 64 + wave * 16;
  const int lm = lane & 15, lq = lane >> 4;
  f32x4_t acc[8];
  #pragma unroll
  for (int i = 0; i < 8; i++) acc[i] = (f32x4_t){0.f, 0.f, 0.f, 0.f};
  gemm_tile_packed(lgsa + (size_t)(r0 + lm) * 128, Wt + 49152, lm, lq, acc);
  #pragma unroll
  for (int nb = 0; nb < 8; nb++){
    int col = nb * 16 + lm;
    u16* gh = (u16*)((nb < 4) ? gat0 : gat1);
    float bb = biasf[col];
    #pragma unroll
    for (int i = 0; i < 4; i++){
      int row = r0 + lq * 4 + i;
      u32 v = lgsa[(size_t)row * 128 + col];
      u16 hb = (u16)(v >> 16);
      float sa = (float)(*(const _Float16*)&hb);
      u16 h = f2bf(fast_tanh(sa + acc[nb][i] + bb));
      gh[((size_t)row * 64 + (col & 63)) * 2 + 1] = h;   // S slot
      lds[wave][lq * 4 + i][col] = h;
    }
  }
  __syncthreads();
  phase2_awlaw(&lds[wave][lm][lq * 8], Wt, biasf, lm, lq, r0, awsa, gat0, gat1);
}

// final: out = tanh(sa + lg@Wl + b), fp32 or bf16 per flag.
__global__ void __launch_bounds__(256) final_out(const u32* __restrict__ lgsa,
    const u16* __restrict__ Wt, const float* __restrict__ biasf,
    const int* __restrict__ flag, void* __restrict__ outp){
  const int lane = threadIdx.x & 63, wave = threadIdx.x >> 6;
  const int r0 = blockIdx.x * 64 + wave * 16;
  const int lm = lane & 15, lq = lane >> 4;
  bool f32out = (*flag != 0);
  f32x4_t acc[8];
  #pragma unroll
  for (int i = 0; i < 8; i++) acc[i] = (f32x4_t){0.f, 0.f, 0.f, 0.f};
  gemm_tile_packed(lgsa + (size_t)(r0 + lm) * 128, Wt + 49152, lm, lq, acc);
  #pragma unroll
  for (int nb = 0; nb < 8; nb++){
    int col = nb * 16 + lm;
    float bb = biasf[col];
    #pragma unroll
    for (int i = 0; i < 4; i++){
      int row = r0 + lq * 4 + i;
      u32 vv = lgsa[(size_t)row * 128 + col];
      u16 hb = (u16)(vv >> 16);
      float sa = (float)(*(const _Float16*)&hb);
      float v = fast_tanh(sa + acc[nb][i] + bb);
      if (f32out) ((float*)outp)[(size_t)row * 128 + col] = v;
      else        ((u16*)  outp)[(size_t)row * 128 + col] = f2bf(v);
    }
  }
}

// ---------------- edge gather: half-channel split, 1 wave/node ----------------
__device__ __forceinline__ void acc_e(u32 g, float& s1, float& s2){
  float el = __uint_as_float(g << 16);
  float sv = __uint_as_float(g & 0xffff0000u);
  s1 += el;
  s2 = fmaf(el, sv, s2);
}

__global__ void __launch_bounds__(256) edge_kernel(const float* __restrict__ awsa,
    const u32* __restrict__ gat0, const u32* __restrict__ gat1,
    const int* __restrict__ row_start, const int* __restrict__ edge_dst,
    u32* __restrict__ lgsa){
  // xcd = blk&7 -> batch = xcd>>1, half = xcd&1: each XCD's gather slab is
  // one batch-half (2.56 MB < 4 MB L2).
  int blk = blockIdx.x;
  int xcd = blk & 7;
  int b = xcd >> 1, h = xcd & 1;
  int i = blk >> 3;                          // 0..2499
  int n = i * 4 + (int)(threadIdx.x >> 6);
  int node = b * NNODE + n;
  int c = threadIdx.x & 63;
  const u32* gh = (h ? gat1 : gat0) + (size_t)b * NNODE * 64;
  int e0 = __builtin_amdgcn_readfirstlane(row_start[b * (NNODE + 1) + n]);
  int e1 = __builtin_amdgcn_readfirstlane(row_start[b * (NNODE + 1) + n + 1]);
  const int* ed = edge_dst + (size_t)b * TWOE;

  float aw = awsa[(size_t)node * 128 + h * 64 + c];
  float ea = __expf(aw);
  float s1 = 0.f, s2 = 0.f, t1 = 0.f, t2 = 0.f;
  int e = e0;
  for (; e + 8 <= e1; e += 8){
    int d0 = ed[e+0], d1 = ed[e+1], d2 = ed[e+2], d3 = ed[e+3];
    int d4 = ed[e+4], d5 = ed[e+5], d6 = ed[e+6], d7 = ed[e+7];
    u32 g0 = gh[(size_t)d0 * 64 + c];
    u32 g1 = gh[(size_t)d1 * 64 + c];
    u32 g2 = gh[(size_t)d2 * 64 + c];
    u32 g3 = gh[(size_t)d3 * 64 + c];
    u32 g4 = gh[(size_t)d4 * 64 + c];
    u32 g5 = gh[(size_t)d5 * 64 + c];
    u32 g6 = gh[(size_t)d6 * 64 + c];
    u32 g7 = gh[(size_t)d7 * 64 + c];
    acc_e(g0, s1, s2); acc_e(g1, t1, t2);
    acc_e(g2, s1, s2); acc_e(g3, t1, t2);
    acc_e(g4, s1, s2); acc_e(g5, t1, t2);
    acc_e(g6, s1, s2); acc_e(g7, t1, t2);
  }
  for (; e < e1; e++){
    u32 gg = gh[(size_t)ed[e] * 64 + c];
    acc_e(gg, s1, s2);
  }
  s1 += t1; s2 += t2;
  float inv = __builtin_amdgcn_rcpf(fmaf(ea, s1, 1.0f));
  float lg = ea * s2 * inv;
  u32 self = gh[(size_t)n * 64 + c];
  float s_self = __uint_as_float(self & 0xffff0000u);
  _Float16 hs = (_Float16)(s_self * inv);
  u32 pk = (u32)f2bf(lg) | ((u32)(*(const u16*)&hs) << 16);
  lgsa[(size_t)node * 128 + h * 64 + c] = pk;
}

// ---------------- host launcher ----------------------------------------------
extern "C" void kernel_launch(void* const* d_in, const int* in_sizes, int n_in,
                              void* d_out, int out_size, void* d_ws, size_t ws_size,
                              hipStream_t stream){
  (void)in_sizes; (void)n_in; (void)ws_size; (void)out_size;
  const void* objects = d_in[0];
  const void* Wo      = d_in[1];
  const void* Wa      = d_in[2];
  const void* Wla     = d_in[3];
  const void* attn_b  = d_in[4];
  const void* Wl      = d_in[5];
  const void* state_b = d_in[6];
  const int*  conn    = (const int*)d_in[7];

  char* base = (char*)d_ws;
  size_t off = 0;
  auto alloc = [&](size_t bytes) -> char* {
    char* p = base + off;
    off = (off + bytes + 255) & ~(size_t)255;
    return p;
  };
  int*   flag      = (int*)  alloc(256);
  u16*   Wt        = (u16*)  alloc((size_t)4 * 16384 * 2);
  float* biasf     = (float*)alloc(256 * 4);
  float* awsa      = (float*)alloc((size_t)MROWS * 128 * 4);   // aW fp32
  u32*   gat0      = (u32*)  alloc((size_t)MROWS * 64 * 4);    // ch 0-63 {EL|S}
  u32*   gat1      = (u32*)  alloc((size_t)MROWS * 64 * 4);    // ch 64-127
  u32*   lgsa      = (u32*)  alloc((size_t)MROWS * 128 * 4);   // {lg bf16 | sa fp16}
  int*   counts    = (int*)  alloc((size_t)MROWS * 4);
  int*   row_start = (int*)  alloc((size_t)BATCH * (NNODE + 1) * 4);
  int*   edge_dst  = (int*)  alloc((size_t)BATCH * TWOE * 4);
  int*   bsum      = (int*)  alloc(160 * 4);
  int*   boff      = (int*)  alloc(160 * 4);

  detect_dtype<<<1, 256, 0, stream>>>((const u32*)objects, flag);
  prep_weights<<<257, 256, 0, stream>>>(Wo, Wa, Wla, Wl, attn_b, state_b, flag, Wt, biasf);

  count_edges<<<128, 256, 0, stream>>>(conn, counts);
  scanA<<<160, 256, 0, stream>>>(counts, row_start, bsum);
  scanB<<<1, 256, 0, stream>>>(bsum, boff, row_start);
  scanC<<<160, 256, 0, stream>>>(row_start, boff);
  fill_edges<<<128, 256, 0, stream>>>(conn, row_start, edge_dst);

  fused_init<<<MROWS / 64, 256, 0, stream>>>(objects, flag, Wt, biasf, awsa, gat0, gat1);
  edge_kernel<<<MROWS / 2, 256, 0, stream>>>(awsa, gat0, gat1, row_start, edge_dst, lgsa);
  fused_mid<<<MROWS / 64, 256, 0, stream>>>(lgsa, Wt, biasf, awsa, gat0, gat1);
  edge_kernel<<<MROWS / 2, 256, 0, stream>>>(awsa, gat0, gat1, row_start, edge_dst, lgsa);
  fused_mid<<<MROWS / 64, 256, 0, stream>>>(lgsa, Wt, biasf, awsa, gat0, gat1);
  edge_kernel<<<MROWS / 2, 256, 0, stream>>>(awsa, gat0, gat1, row_start, edge_dst, lgsa);
  final_out<<<MROWS / 64, 256, 0, stream>>>(lgsa, Wt, biasf, flag, d_out);
}

// Round 7
// 416.958 us; speedup vs baseline: 1.7676x; 1.7676x over previous
//
#include <hip/hip_runtime.h>
#include <hip/hip_bf16.h>

// AttentiveGraph: B=4, N=10000, E=160000, C=F=128, 3 iterations.
// R7: CSR build rebuilt as deterministic 3-phase chunked histogram —
// each edge read ONCE (R6's windowed build re-scanned conn 16x at 2
// waves/CU: 460us). Phase A: per-chunk LDS hist -> u16 partial rows.
// Phase B: per-node chunk-prefix scan + window scan. Phase C: LDS
// cursors, place edges. Zero global atomics; writes batch-slab-local
// (XCD swizzle). Rest identical to R6 (fixed packed GEMMs, half-channel
// L2-resident edge gather).

#define BATCH 4
#define NNODE 10000
#define NEDGE 160000
#define TWOE  (2*NEDGE)
#define MROWS (BATCH*NNODE)   // 40000
#define NCHUNK 64
#define CHUNKE (NEDGE/NCHUNK) // 2500
#define PADN  10240

typedef unsigned short u16;
typedef unsigned int   u32;
typedef __attribute__((ext_vector_type(8))) short bf16x8_t;
typedef __attribute__((ext_vector_type(4))) float f32x4_t;

__device__ __forceinline__ float b2f(u16 h){ return __uint_as_float(((u32)h) << 16); }
__device__ __forceinline__ u16 f2bf(float f){
  u32 u = __float_as_uint(f);
  return (u16)((u + 0x7fffu + ((u >> 16) & 1u)) >> 16);   // RNE
}
__device__ __forceinline__ float fast_tanh(float x){
  float e = __expf(2.0f * x);
  return fmaf(-2.0f, __builtin_amdgcn_rcpf(e + 1.0f), 1.0f);
}

// ---------------- storage dtype probe (fp32 vs bf16 storage) ------------------
__global__ void detect_dtype(const u32* __restrict__ objw, int* __restrict__ flag){
  __shared__ int zc, hc;
  if (threadIdx.x == 0){ zc = 0; hc = 0; }
  __syncthreads();
  int z = 0, h = 0;
  for (int i = threadIdx.x; i < 1024; i += 256){
    u32 lo = objw[i] & 0xffffu;
    if (lo == 0) z++;
    if (((lo >> 7) & 0xffu) >= 160u) h++;
  }
  atomicAdd(&zc, z); atomicAdd(&hc, h);
  __syncthreads();
  if (threadIdx.x == 0) *flag = (hc > 0 || zc > 512) ? 1 : 0;   // 1 = fp32 storage
}

// Wt[m][c*128+k] = W_m[k*128+c]; tail block converts biases.
__global__ void prep_weights(const void* __restrict__ Wo, const void* __restrict__ Wa,
                             const void* __restrict__ Wla, const void* __restrict__ Wl,
                             const void* __restrict__ ab, const void* __restrict__ sb,
                             const int* __restrict__ flag, u16* __restrict__ Wt,
                             float* __restrict__ biasf){
  int idx = blockIdx.x * 256 + threadIdx.x;
  bool f = (*flag != 0);
  if (idx < 65536){
    int m = idx >> 14, k = (idx >> 7) & 127, c = idx & 127;
    const void* src = (m == 0) ? Wo : (m == 1) ? Wa : (m == 2) ? Wla : Wl;
    u16 h = f ? f2bf(((const float*)src)[k * 128 + c]) : ((const u16*)src)[k * 128 + c];
    Wt[m * 16384 + c * 128 + k] = h;
  } else {
    int t = idx - 65536;
    const void* src = (t < 128) ? sb : ab;
    int i = t & 127;
    biasf[t] = f ? ((const float*)src)[i] : b2f(((const u16*)src)[i]);
  }
}

// ---------------- CSR build: 3-phase chunked histogram ------------------------
// Block swizzle (256 blocks): xcd=blk&7 -> batch=xcd>>1; chunk=((blk>>3)<<1)|(xcd&1).
__device__ __forceinline__ void chunk_of(int blk, int& b, int& c){
  int xcd = blk & 7;
  b = xcd >> 1;
  c = ((blk >> 3) << 1) | (xcd & 1);           // 0..63
}

// Phase A: per-chunk histogram -> partial[b][c][n] (u16, coalesced row)
__global__ void __launch_bounds__(256) csr_hist(const int* __restrict__ conn,
                                                u16* __restrict__ partial){
  int b, c; chunk_of(blockIdx.x, b, c);
  __shared__ u32 hist[NNODE];
  for (int n = threadIdx.x; n < NNODE; n += 256) hist[n] = 0;
  __syncthreads();
  const int2* cp = (const int2*)conn + (size_t)b * NEDGE + c * CHUNKE;
  for (int i = threadIdx.x; i < CHUNKE; i += 256){
    int2 e = cp[i];
    atomicAdd(&hist[e.x], 1);
    atomicAdd(&hist[e.y], 1);
  }
  __syncthreads();
  u16* prow = partial + (size_t)(b * NCHUNK + c) * PADN;
  for (int n = threadIdx.x; n < NNODE; n += 256) prow[n] = (u16)hist[n];
}

// Phase B1: per-node exclusive prefix over chunks (in-place) + window scan.
__global__ void __launch_bounds__(256) csr_colscan(u16* __restrict__ partial,
    int* __restrict__ row_start, int* __restrict__ bsum){
  int b = blockIdx.x / 40, w = blockIdx.x % 40;
  int n = w * 256 + threadIdx.x;
  u32 run = 0;
  if (n < NNODE){
    #pragma unroll 8
    for (int c = 0; c < NCHUNK; c++){
      size_t idx = (size_t)(b * NCHUNK + c) * PADN + n;
      u32 v = partial[idx];
      partial[idx] = (u16)run;
      run += v;
    }
  }
  __shared__ u32 buf[256];
  buf[threadIdx.x] = run;
  __syncthreads();
  for (int off = 1; off < 256; off <<= 1){
    u32 x = (threadIdx.x >= (unsigned)off) ? buf[threadIdx.x - off] : 0;
    __syncthreads();
    buf[threadIdx.x] += x;
    __syncthreads();
  }
  u32 incl = buf[threadIdx.x];
  if (n < NNODE) row_start[b * (NNODE + 1) + n] = (int)(incl - run);  // window-local
  if (threadIdx.x == 255) bsum[blockIdx.x] = (int)incl;
}

// Phase B2: offsets across 40 windows per batch. 1 block.
__global__ void scanB(const int* __restrict__ bsum, int* __restrict__ boff,
                      int* __restrict__ row_start){
  __shared__ int s[160];
  if (threadIdx.x < 160) s[threadIdx.x] = bsum[threadIdx.x];
  __syncthreads();
  if (threadIdx.x < 160){
    int b = threadIdx.x / 40, j = threadIdx.x % 40;
    int off = 0;
    for (int q = b * 40; q < b * 40 + j; q++) off += s[q];
    boff[threadIdx.x] = off;
  }
  if (threadIdx.x < BATCH) row_start[threadIdx.x * (NNODE + 1) + NNODE] = TWOE;
}

// Phase B3: finalize global row_start.
__global__ void scanC(int* __restrict__ row_start, const int* __restrict__ boff){
  int b = blockIdx.x / 40, j = blockIdx.x % 40;
  int n = j * 256 + threadIdx.x;
  if (n < NNODE) row_start[b * (NNODE + 1) + n] += boff[blockIdx.x];
}

// Phase C: LDS cursors = row_start + chunk prefix; place edges.
__global__ void __launch_bounds__(256) csr_fill(const int* __restrict__ conn,
    const u16* __restrict__ partial, const int* __restrict__ row_start,
    int* __restrict__ edge_dst){
  int b, c; chunk_of(blockIdx.x, b, c);
  __shared__ u32 cur[NNODE];
  const u16* prow = partial + (size_t)(b * NCHUNK + c) * PADN;
  const int* rs = row_start + b * (NNODE + 1);
  for (int n = threadIdx.x; n < NNODE; n += 256) cur[n] = (u32)rs[n] + prow[n];
  __syncthreads();
  const int2* cp = (const int2*)conn + (size_t)b * NEDGE + c * CHUNKE;
  int* edb = edge_dst + (size_t)b * TWOE;
  for (int i = threadIdx.x; i < CHUNKE; i += 256){
    int2 e = cp[i];
    u32 p1 = atomicAdd(&cur[e.x], 1); edb[p1] = e.y;
    u32 p2 = atomicAdd(&cur[e.y], 1); edb[p2] = e.x;
  }
}

// ---------------- MFMA helpers (wave = 16 rows x 128 cols) --------------------
__device__ __forceinline__ void gemm_tile(const u16* __restrict__ arow,
    const u16* __restrict__ wt, int lm, int lq, f32x4_t acc[8]){
  #pragma unroll
  for (int ks = 0; ks < 4; ks++){
    bf16x8_t a = *(const bf16x8_t*)(arow + ks * 32);
    #pragma unroll
    for (int nb = 0; nb < 8; nb++){
      bf16x8_t bfr = *(const bf16x8_t*)(wt + (nb * 16 + lm) * 128 + ks * 32 + lq * 8);
      acc[nb] = __builtin_amdgcn_mfma_f32_16x16x32_bf16(a, bfr, acc[nb], 0, 0, 0);
    }
  }
}

// A-frag from packed lgsa (lg = low u16 of each u32). Lrow = row base ONLY.
__device__ __forceinline__ void gemm_tile_packed(const u32* __restrict__ Lrow,
    const u16* __restrict__ wt, int lm, int lq, f32x4_t acc[8]){
  #pragma unroll
  for (int ks = 0; ks < 4; ks++){
    uint4 wa = *(const uint4*)(Lrow + ks * 32 + lq * 8);
    uint4 wb = *(const uint4*)(Lrow + ks * 32 + lq * 8 + 4);
    bf16x8_t a;
    a[0] = (short)wa.x; a[1] = (short)wa.y; a[2] = (short)wa.z; a[3] = (short)wa.w;
    a[4] = (short)wb.x; a[5] = (short)wb.y; a[6] = (short)wb.z; a[7] = (short)wb.w;
    #pragma unroll
    for (int nb = 0; nb < 8; nb++){
      bf16x8_t bfr = *(const bf16x8_t*)(wt + (nb * 16 + lm) * 128 + ks * 32 + lq * 8);
      acc[nb] = __builtin_amdgcn_mfma_f32_16x16x32_bf16(a, bfr, acc[nb], 0, 0, 0);
    }
  }
}

// phase 2: states tile (LDS, A-layout) -> aW fp32 + EL slots in gat halves
__device__ __forceinline__ void phase2_awlaw(const u16* __restrict__ ldsrow,
    const u16* __restrict__ Wt, const float* __restrict__ biasf,
    int lm, int lq, int r0, float* __restrict__ awsa,
    u32* __restrict__ gat0, u32* __restrict__ gat1){
  const u16* Wta  = Wt + 16384;
  const u16* Wtla = Wt + 32768;
  f32x4_t accA[8], accL[8];
  #pragma unroll
  for (int i = 0; i < 8; i++){ accA[i] = (f32x4_t){0.f,0.f,0.f,0.f}; accL[i] = (f32x4_t){0.f,0.f,0.f,0.f}; }
  #pragma unroll
  for (int ks = 0; ks < 4; ks++){
    bf16x8_t a = *(const bf16x8_t*)(ldsrow + ks * 32);
    #pragma unroll
    for (int nb = 0; nb < 8; nb++){
      bf16x8_t ba = *(const bf16x8_t*)(Wta  + (nb * 16 + lm) * 128 + ks * 32 + lq * 8);
      bf16x8_t bl = *(const bf16x8_t*)(Wtla + (nb * 16 + lm) * 128 + ks * 32 + lq * 8);
      accA[nb] = __builtin_amdgcn_mfma_f32_16x16x32_bf16(a, ba, accA[nb], 0, 0, 0);
      accL[nb] = __builtin_amdgcn_mfma_f32_16x16x32_bf16(a, bl, accL[nb], 0, 0, 0);
    }
  }
  #pragma unroll
  for (int nb = 0; nb < 8; nb++){
    int col = nb * 16 + lm;
    u16* gh = (u16*)((nb < 4) ? gat0 : gat1);
    float bb = biasf[128 + col];
    #pragma unroll
    for (int i = 0; i < 4; i++){
      int row = r0 + lq * 4 + i;
      awsa[(size_t)row * 128 + col] = accA[nb][i];
      gh[((size_t)row * 64 + (col & 63)) * 2] = f2bf(__expf(accL[nb][i] + bb));  // EL slot
    }
  }
}

// init: states = tanh(obj@Wo + b) from raw objects; then aW/EL.
__global__ void __launch_bounds__(256) fused_init(const void* __restrict__ obj_raw,
    const int* __restrict__ flag, const u16* __restrict__ Wt,
    const float* __restrict__ biasf, float* __restrict__ awsa,
    u32* __restrict__ gat0, u32* __restrict__ gat1){
  __shared__ u16 lds[4][16][136];
  const int lane = threadIdx.x & 63, wave = threadIdx.x >> 6;
  const int r0 = blockIdx.x * 64 + wave * 16;
  const int lm = lane & 15, lq = lane >> 4;
  f32x4_t acc[8];
  #pragma unroll
  for (int i = 0; i < 8; i++) acc[i] = (f32x4_t){0.f, 0.f, 0.f, 0.f};
  if (*flag){
    const float* arow = (const float*)obj_raw + (size_t)(r0 + lm) * 128 + lq * 8;
    #pragma unroll
    for (int ks = 0; ks < 4; ks++){
      float4 fa = *(const float4*)(arow + ks * 32);
      float4 fb = *(const float4*)(arow + ks * 32 + 4);
      bf16x8_t a;
      a[0] = (short)f2bf(fa.x); a[1] = (short)f2bf(fa.y);
      a[2] = (short)f2bf(fa.z); a[3] = (short)f2bf(fa.w);
      a[4] = (short)f2bf(fb.x); a[5] = (short)f2bf(fb.y);
      a[6] = (short)f2bf(fb.z); a[7] = (short)f2bf(fb.w);
      #pragma unroll
      for (int nb = 0; nb < 8; nb++){
        bf16x8_t bfr = *(const bf16x8_t*)(Wt + (nb * 16 + lm) * 128 + ks * 32 + lq * 8);
        acc[nb] = __builtin_amdgcn_mfma_f32_16x16x32_bf16(a, bfr, acc[nb], 0, 0, 0);
      }
    }
  } else {
    gemm_tile((const u16*)obj_raw + (size_t)(r0 + lm) * 128 + lq * 8, Wt, lm, lq, acc);
  }
  #pragma unroll
  for (int nb = 0; nb < 8; nb++){
    int col = nb * 16 + lm;
    u16* gh = (u16*)((nb < 4) ? gat0 : gat1);
    float bb = biasf[col];
    #pragma unroll
    for (int i = 0; i < 4; i++){
      int row = r0 + lq * 4 + i;
      u16 h = f2bf(fast_tanh(acc[nb][i] + bb));
      gh[((size_t)row * 64 + (col & 63)) * 2 + 1] = h;   // S slot
      lds[wave][lq * 4 + i][col] = h;
    }
  }
  __syncthreads();
  phase2_awlaw(&lds[wave][lm][lq * 8], Wt, biasf, lm, lq, r0, awsa, gat0, gat1);
}

// mid: states = tanh(sa + lg@Wl + b); then aW/EL for next iter.
__global__ void __launch_bounds__(256) fused_mid(const u32* __restrict__ lgsa,
    const u16* __restrict__ Wt, const float* __restrict__ biasf,
    float* __restrict__ awsa, u32* __restrict__ gat0, u32* __restrict__ gat1){
  __shared__ u16 lds[4][16][136];
  const int lane = threadIdx.x & 63, wave = threadIdx.x >> 6;
  const int r0 = blockIdx.x * 64 + wave * 16;
  const int lm = lane & 15, lq = lane >> 4;
  f32x4_t acc[8];
  #pragma unroll
  for (int i = 0; i < 8; i++) acc[i] = (f32x4_t){0.f, 0.f, 0.f, 0.f};
  gemm_tile_packed(lgsa + (size_t)(r0 + lm) * 128, Wt + 49152, lm, lq, acc);
  #pragma unroll
  for (int nb = 0; nb < 8; nb++){
    int col = nb * 16 + lm;
    u16* gh = (u16*)((nb < 4) ? gat0 : gat1);
    float bb = biasf[col];
    #pragma unroll
    for (int i = 0; i < 4; i++){
      int row = r0 + lq * 4 + i;
      u32 v = lgsa[(size_t)row * 128 + col];
      u16 hb = (u16)(v >> 16);
      float sa = (float)(*(const _Float16*)&hb);
      u16 h = f2bf(fast_tanh(sa + acc[nb][i] + bb));
      gh[((size_t)row * 64 + (col & 63)) * 2 + 1] = h;   // S slot
      lds[wave][lq * 4 + i][col] = h;
    }
  }
  __syncthreads();
  phase2_awlaw(&lds[wave][lm][lq * 8], Wt, biasf, lm, lq, r0, awsa, gat0, gat1);
}

// final: out = tanh(sa + lg@Wl + b), fp32 or bf16 per flag.
__global__ void __launch_bounds__(256) final_out(const u32* __restrict__ lgsa,
    const u16* __restrict__ Wt, const float* __restrict__ biasf,
    const int* __restrict__ flag, void* __restrict__ outp){
  const int lane = threadIdx.x & 63, wave = threadIdx.x >> 6;
  const int r0 = blockIdx.x * 64 + wave * 16;
  const int lm = lane & 15, lq = lane >> 4;
  bool f32out = (*flag != 0);
  f32x4_t acc[8];
  #pragma unroll
  for (int i = 0; i < 8; i++) acc[i] = (f32x4_t){0.f, 0.f, 0.f, 0.f};
  gemm_tile_packed(lgsa + (size_t)(r0 + lm) * 128, Wt + 49152, lm, lq, acc);
  #pragma unroll
  for (int nb = 0; nb < 8; nb++){
    int col = nb * 16 + lm;
    float bb = biasf[col];
    #pragma unroll
    for (int i = 0; i < 4; i++){
      int row = r0 + lq * 4 + i;
      u32 vv = lgsa[(size_t)row * 128 + col];
      u16 hb = (u16)(vv >> 16);
      float sa = (float)(*(const _Float16*)&hb);
      float v = fast_tanh(sa + acc[nb][i] + bb);
      if (f32out) ((float*)outp)[(size_t)row * 128 + col] = v;
      else        ((u16*)  outp)[(size_t)row * 128 + col] = f2bf(v);
    }
  }
}

// ---------------- edge gather: half-channel split, 1 wave/node ----------------
__device__ __forceinline__ void acc_e(u32 g, float& s1, float& s2){
  float el = __uint_as_float(g << 16);
  float sv = __uint_as_float(g & 0xffff0000u);
  s1 += el;
  s2 = fmaf(el, sv, s2);
}

__global__ void __launch_bounds__(256) edge_kernel(const float* __restrict__ awsa,
    const u32* __restrict__ gat0, const u32* __restrict__ gat1,
    const int* __restrict__ row_start, const int* __restrict__ edge_dst,
    u32* __restrict__ lgsa){
  int blk = blockIdx.x;
  int xcd = blk & 7;
  int b = xcd >> 1, h = xcd & 1;
  int i = blk >> 3;                          // 0..2499
  int n = i * 4 + (int)(threadIdx.x >> 6);
  int node = b * NNODE + n;
  int c = threadIdx.x & 63;
  const u32* gh = (h ? gat1 : gat0) + (size_t)b * NNODE * 64;
  int e0 = __builtin_amdgcn_readfirstlane(row_start[b * (NNODE + 1) + n]);
  int e1 = __builtin_amdgcn_readfirstlane(row_start[b * (NNODE + 1) + n + 1]);
  const int* ed = edge_dst + (size_t)b * TWOE;

  float aw = awsa[(size_t)node * 128 + h * 64 + c];
  float ea = __expf(aw);
  float s1 = 0.f, s2 = 0.f, t1 = 0.f, t2 = 0.f;
  int e = e0;
  for (; e + 8 <= e1; e += 8){
    int d0 = ed[e+0], d1 = ed[e+1], d2 = ed[e+2], d3 = ed[e+3];
    int d4 = ed[e+4], d5 = ed[e+5], d6 = ed[e+6], d7 = ed[e+7];
    u32 g0 = gh[(size_t)d0 * 64 + c];
    u32 g1 = gh[(size_t)d1 * 64 + c];
    u32 g2 = gh[(size_t)d2 * 64 + c];
    u32 g3 = gh[(size_t)d3 * 64 + c];
    u32 g4 = gh[(size_t)d4 * 64 + c];
    u32 g5 = gh[(size_t)d5 * 64 + c];
    u32 g6 = gh[(size_t)d6 * 64 + c];
    u32 g7 = gh[(size_t)d7 * 64 + c];
    acc_e(g0, s1, s2); acc_e(g1, t1, t2);
    acc_e(g2, s1, s2); acc_e(g3, t1, t2);
    acc_e(g4, s1, s2); acc_e(g5, t1, t2);
    acc_e(g6, s1, s2); acc_e(g7, t1, t2);
  }
  for (; e < e1; e++){
    u32 gg = gh[(size_t)ed[e] * 64 + c];
    acc_e(gg, s1, s2);
  }
  s1 += t1; s2 += t2;
  float inv = __builtin_amdgcn_rcpf(fmaf(ea, s1, 1.0f));
  float lg = ea * s2 * inv;
  u32 self = gh[(size_t)n * 64 + c];
  float s_self = __uint_as_float(self & 0xffff0000u);
  _Float16 hs = (_Float16)(s_self * inv);
  u32 pk = (u32)f2bf(lg) | ((u32)(*(const u16*)&hs) << 16);
  lgsa[(size_t)node * 128 + h * 64 + c] = pk;
}

// ---------------- host launcher ----------------------------------------------
extern "C" void kernel_launch(void* const* d_in, const int* in_sizes, int n_in,
                              void* d_out, int out_size, void* d_ws, size_t ws_size,
                              hipStream_t stream){
  (void)in_sizes; (void)n_in; (void)ws_size; (void)out_size;
  const void* objects = d_in[0];
  const void* Wo      = d_in[1];
  const void* Wa      = d_in[2];
  const void* Wla     = d_in[3];
  const void* attn_b  = d_in[4];
  const void* Wl      = d_in[5];
  const void* state_b = d_in[6];
  const int*  conn    = (const int*)d_in[7];

  char* base = (char*)d_ws;
  size_t off = 0;
  auto alloc = [&](size_t bytes) -> char* {
    char* p = base + off;
    off = (off + bytes + 255) & ~(size_t)255;
    return p;
  };
  int*   flag      = (int*)  alloc(256);
  u16*   Wt        = (u16*)  alloc((size_t)4 * 16384 * 2);
  float* biasf     = (float*)alloc(256 * 4);
  float* awsa      = (float*)alloc((size_t)MROWS * 128 * 4);   // aW fp32
  u32*   gat0      = (u32*)  alloc((size_t)MROWS * 64 * 4);    // ch 0-63 {EL|S}
  u32*   gat1      = (u32*)  alloc((size_t)MROWS * 64 * 4);    // ch 64-127
  u32*   lgsa      = (u32*)  alloc((size_t)MROWS * 128 * 4);   // {lg bf16 | sa fp16}
  u16*   partial   = (u16*)  alloc((size_t)BATCH * NCHUNK * PADN * 2);
  int*   row_start = (int*)  alloc((size_t)BATCH * (NNODE + 1) * 4);
  int*   edge_dst  = (int*)  alloc((size_t)BATCH * TWOE * 4);
  int*   bsum      = (int*)  alloc(160 * 4);
  int*   boff      = (int*)  alloc(160 * 4);

  detect_dtype<<<1, 256, 0, stream>>>((const u32*)objects, flag);
  prep_weights<<<257, 256, 0, stream>>>(Wo, Wa, Wla, Wl, attn_b, state_b, flag, Wt, biasf);

  csr_hist<<<256, 256, 0, stream>>>(conn, partial);
  csr_colscan<<<160, 256, 0, stream>>>(partial, row_start, bsum);
  scanB<<<1, 256, 0, stream>>>(bsum, boff, row_start);
  scanC<<<160, 256, 0, stream>>>(row_start, boff);
  csr_fill<<<256, 256, 0, stream>>>(conn, partial, row_start, edge_dst);

  fused_init<<<MROWS / 64, 256, 0, stream>>>(objects, flag, Wt, biasf, awsa, gat0, gat1);
  edge_kernel<<<MROWS / 2, 256, 0, stream>>>(awsa, gat0, gat1, row_start, edge_dst, lgsa);
  fused_mid<<<MROWS / 64, 256, 0, stream>>>(lgsa, Wt, biasf, awsa, gat0, gat1);
  edge_kernel<<<MROWS / 2, 256, 0, stream>>>(awsa, gat0, gat1, row_start, edge_dst, lgsa);
  fused_mid<<<MROWS / 64, 256, 0, stream>>>(lgsa, Wt, biasf, awsa, gat0, gat1);
  edge_kernel<<<MROWS / 2, 256, 0, stream>>>(awsa, gat0, gat1, row_start, edge_dst, lgsa);
  final_out<<<MROWS / 64, 256, 0, stream>>>(lgsa, Wt, biasf, flag, d_out);
}

// Round 8
// 411.545 us; speedup vs baseline: 1.7908x; 1.0132x over previous
//
#include <hip/hip_runtime.h>
#include <hip/hip_bf16.h>

// AttentiveGraph: B=4, N=10000, E=160000, C=F=128, 3 iterations.
// R8: fused GEMM kernels column-split — wave = 16 rows x 64 cols (was 128),
// grid 625->1250 blocks, 2500->5000 waves (R7: OccupancyPercent 8%,
// latency-bound epilogue stores). phase2 writes single u32 {EL|S} (S pulled
// back from LDS tile) instead of two 2-B partial-word stores. final_out
// col-split too. CSR (R7 3-phase chunked histogram) + edge kernel unchanged.

#define BATCH 4
#define NNODE 10000
#define NEDGE 160000
#define TWOE  (2*NEDGE)
#define MROWS (BATCH*NNODE)   // 40000
#define NCHUNK 64
#define CHUNKE (NEDGE/NCHUNK) // 2500
#define PADN  10240

typedef unsigned short u16;
typedef unsigned int   u32;
typedef __attribute__((ext_vector_type(8))) short bf16x8_t;
typedef __attribute__((ext_vector_type(4))) float f32x4_t;

__device__ __forceinline__ float b2f(u16 h){ return __uint_as_float(((u32)h) << 16); }
__device__ __forceinline__ u16 f2bf(float f){
  u32 u = __float_as_uint(f);
  return (u16)((u + 0x7fffu + ((u >> 16) & 1u)) >> 16);   // RNE
}
__device__ __forceinline__ float fast_tanh(float x){
  float e = __expf(2.0f * x);
  return fmaf(-2.0f, __builtin_amdgcn_rcpf(e + 1.0f), 1.0f);
}

// ---------------- storage dtype probe (fp32 vs bf16 storage) ------------------
__global__ void detect_dtype(const u32* __restrict__ objw, int* __restrict__ flag){
  __shared__ int zc, hc;
  if (threadIdx.x == 0){ zc = 0; hc = 0; }
  __syncthreads();
  int z = 0, h = 0;
  for (int i = threadIdx.x; i < 1024; i += 256){
    u32 lo = objw[i] & 0xffffu;
    if (lo == 0) z++;
    if (((lo >> 7) & 0xffu) >= 160u) h++;
  }
  atomicAdd(&zc, z); atomicAdd(&hc, h);
  __syncthreads();
  if (threadIdx.x == 0) *flag = (hc > 0 || zc > 512) ? 1 : 0;   // 1 = fp32 storage
}

// Wt[m][c*128+k] = W_m[k*128+c]; tail block converts biases.
__global__ void prep_weights(const void* __restrict__ Wo, const void* __restrict__ Wa,
                             const void* __restrict__ Wla, const void* __restrict__ Wl,
                             const void* __restrict__ ab, const void* __restrict__ sb,
                             const int* __restrict__ flag, u16* __restrict__ Wt,
                             float* __restrict__ biasf){
  int idx = blockIdx.x * 256 + threadIdx.x;
  bool f = (*flag != 0);
  if (idx < 65536){
    int m = idx >> 14, k = (idx >> 7) & 127, c = idx & 127;
    const void* src = (m == 0) ? Wo : (m == 1) ? Wa : (m == 2) ? Wla : Wl;
    u16 h = f ? f2bf(((const float*)src)[k * 128 + c]) : ((const u16*)src)[k * 128 + c];
    Wt[m * 16384 + c * 128 + k] = h;
  } else {
    int t = idx - 65536;
    const void* src = (t < 128) ? sb : ab;
    int i = t & 127;
    biasf[t] = f ? ((const float*)src)[i] : b2f(((const u16*)src)[i]);
  }
}

// ---------------- CSR build: 3-phase chunked histogram ------------------------
__device__ __forceinline__ void chunk_of(int blk, int& b, int& c){
  int xcd = blk & 7;
  b = xcd >> 1;
  c = ((blk >> 3) << 1) | (xcd & 1);           // 0..63
}

__global__ void __launch_bounds__(256) csr_hist(const int* __restrict__ conn,
                                                u16* __restrict__ partial){
  int b, c; chunk_of(blockIdx.x, b, c);
  __shared__ u32 hist[NNODE];
  for (int n = threadIdx.x; n < NNODE; n += 256) hist[n] = 0;
  __syncthreads();
  const int2* cp = (const int2*)conn + (size_t)b * NEDGE + c * CHUNKE;
  for (int i = threadIdx.x; i < CHUNKE; i += 256){
    int2 e = cp[i];
    atomicAdd(&hist[e.x], 1);
    atomicAdd(&hist[e.y], 1);
  }
  __syncthreads();
  u16* prow = partial + (size_t)(b * NCHUNK + c) * PADN;
  for (int n = threadIdx.x; n < NNODE; n += 256) prow[n] = (u16)hist[n];
}

__global__ void __launch_bounds__(256) csr_colscan(u16* __restrict__ partial,
    int* __restrict__ row_start, int* __restrict__ bsum){
  int b = blockIdx.x / 40, w = blockIdx.x % 40;
  int n = w * 256 + threadIdx.x;
  u32 run = 0;
  if (n < NNODE){
    #pragma unroll 8
    for (int c = 0; c < NCHUNK; c++){
      size_t idx = (size_t)(b * NCHUNK + c) * PADN + n;
      u32 v = partial[idx];
      partial[idx] = (u16)run;
      run += v;
    }
  }
  __shared__ u32 buf[256];
  buf[threadIdx.x] = run;
  __syncthreads();
  for (int off = 1; off < 256; off <<= 1){
    u32 x = (threadIdx.x >= (unsigned)off) ? buf[threadIdx.x - off] : 0;
    __syncthreads();
    buf[threadIdx.x] += x;
    __syncthreads();
  }
  u32 incl = buf[threadIdx.x];
  if (n < NNODE) row_start[b * (NNODE + 1) + n] = (int)(incl - run);  // window-local
  if (threadIdx.x == 255) bsum[blockIdx.x] = (int)incl;
}

__global__ void scanB(const int* __restrict__ bsum, int* __restrict__ boff,
                      int* __restrict__ row_start){
  __shared__ int s[160];
  if (threadIdx.x < 160) s[threadIdx.x] = bsum[threadIdx.x];
  __syncthreads();
  if (threadIdx.x < 160){
    int b = threadIdx.x / 40, j = threadIdx.x % 40;
    int off = 0;
    for (int q = b * 40; q < b * 40 + j; q++) off += s[q];
    boff[threadIdx.x] = off;
  }
  if (threadIdx.x < BATCH) row_start[threadIdx.x * (NNODE + 1) + NNODE] = TWOE;
}

__global__ void scanC(int* __restrict__ row_start, const int* __restrict__ boff){
  int b = blockIdx.x / 40, j = blockIdx.x % 40;
  int n = j * 256 + threadIdx.x;
  if (n < NNODE) row_start[b * (NNODE + 1) + n] += boff[blockIdx.x];
}

__global__ void __launch_bounds__(256) csr_fill(const int* __restrict__ conn,
    const u16* __restrict__ partial, const int* __restrict__ row_start,
    int* __restrict__ edge_dst){
  int b, c; chunk_of(blockIdx.x, b, c);
  __shared__ u32 cur[NNODE];
  const u16* prow = partial + (size_t)(b * NCHUNK + c) * PADN;
  const int* rs = row_start + b * (NNODE + 1);
  for (int n = threadIdx.x; n < NNODE; n += 256) cur[n] = (u32)rs[n] + prow[n];
  __syncthreads();
  const int2* cp = (const int2*)conn + (size_t)b * NEDGE + c * CHUNKE;
  int* edb = edge_dst + (size_t)b * TWOE;
  for (int i = threadIdx.x; i < CHUNKE; i += 256){
    int2 e = cp[i];
    u32 p1 = atomicAdd(&cur[e.x], 1); edb[p1] = e.y;
    u32 p2 = atomicAdd(&cur[e.y], 1); edb[p2] = e.x;
  }
}

// ---------------- MFMA helpers (wave = 16 rows x 64 cols, col-split) ----------
// cofs = col-half offset (0 or 64). 4 MFMA col-blocks per wave.
__device__ __forceinline__ void gemm_tile4(const u16* __restrict__ arow,
    const u16* __restrict__ wt, int lm, int lq, int cofs, f32x4_t acc[4]){
  #pragma unroll
  for (int ks = 0; ks < 4; ks++){
    bf16x8_t a = *(const bf16x8_t*)(arow + ks * 32);
    #pragma unroll
    for (int nb = 0; nb < 4; nb++){
      bf16x8_t bfr = *(const bf16x8_t*)(wt + (cofs + nb * 16 + lm) * 128 + ks * 32 + lq * 8);
      acc[nb] = __builtin_amdgcn_mfma_f32_16x16x32_bf16(a, bfr, acc[nb], 0, 0, 0);
    }
  }
}

// A-frag from packed lgsa (lg = low u16 of each u32). Lrow = row base ONLY.
__device__ __forceinline__ void gemm_tile4_packed(const u32* __restrict__ Lrow,
    const u16* __restrict__ wt, int lm, int lq, int cofs, f32x4_t acc[4]){
  #pragma unroll
  for (int ks = 0; ks < 4; ks++){
    uint4 wa = *(const uint4*)(Lrow + ks * 32 + lq * 8);
    uint4 wb = *(const uint4*)(Lrow + ks * 32 + lq * 8 + 4);
    bf16x8_t a;
    a[0] = (short)wa.x; a[1] = (short)wa.y; a[2] = (short)wa.z; a[3] = (short)wa.w;
    a[4] = (short)wb.x; a[5] = (short)wb.y; a[6] = (short)wb.z; a[7] = (short)wb.w;
    #pragma unroll
    for (int nb = 0; nb < 4; nb++){
      bf16x8_t bfr = *(const bf16x8_t*)(wt + (cofs + nb * 16 + lm) * 128 + ks * 32 + lq * 8);
      acc[nb] = __builtin_amdgcn_mfma_f32_16x16x32_bf16(a, bfr, acc[nb], 0, 0, 0);
    }
  }
}

// phase 2: states tile (LDS, A-layout) -> aW fp32 + single-u32 {EL|S} gat store.
// ldstile = &lds[t][0][0] (stride 136 u16 per row).
__device__ __forceinline__ void phase2_awlaw4(const u16* __restrict__ ldstile,
    const u16* __restrict__ Wt, const float* __restrict__ biasf,
    int lm, int lq, int cofs, int r0, float* __restrict__ awsa,
    u32* __restrict__ ghw){
  const u16* Wta  = Wt + 16384;
  const u16* Wtla = Wt + 32768;
  const u16* ldsrow = ldstile + lm * 136 + lq * 8;
  f32x4_t accA[4], accL[4];
  #pragma unroll
  for (int i = 0; i < 4; i++){ accA[i] = (f32x4_t){0.f,0.f,0.f,0.f}; accL[i] = (f32x4_t){0.f,0.f,0.f,0.f}; }
  #pragma unroll
  for (int ks = 0; ks < 4; ks++){
    bf16x8_t a = *(const bf16x8_t*)(ldsrow + ks * 32);
    #pragma unroll
    for (int nb = 0; nb < 4; nb++){
      bf16x8_t ba = *(const bf16x8_t*)(Wta  + (cofs + nb * 16 + lm) * 128 + ks * 32 + lq * 8);
      bf16x8_t bl = *(const bf16x8_t*)(Wtla + (cofs + nb * 16 + lm) * 128 + ks * 32 + lq * 8);
      accA[nb] = __builtin_amdgcn_mfma_f32_16x16x32_bf16(a, ba, accA[nb], 0, 0, 0);
      accL[nb] = __builtin_amdgcn_mfma_f32_16x16x32_bf16(a, bl, accL[nb], 0, 0, 0);
    }
  }
  #pragma unroll
  for (int nb = 0; nb < 4; nb++){
    int col = cofs + nb * 16 + lm;
    float bb = biasf[128 + col];
    #pragma unroll
    for (int i = 0; i < 4; i++){
      int row = r0 + lq * 4 + i;
      awsa[(size_t)row * 128 + col] = accA[nb][i];
      u16 el = f2bf(__expf(accL[nb][i] + bb));
      u16 s  = ldstile[(lq * 4 + i) * 136 + col];
      ghw[(size_t)row * 64 + (col & 63)] = (u32)el | ((u32)s << 16);
    }
  }
}

// init: states = tanh(obj@Wo + b) from raw objects; then aW/EL/S.
__global__ void __launch_bounds__(256) fused_init(const void* __restrict__ obj_raw,
    const int* __restrict__ flag, const u16* __restrict__ Wt,
    const float* __restrict__ biasf, float* __restrict__ awsa,
    u32* __restrict__ gat0, u32* __restrict__ gat1){
  __shared__ u16 lds[2][16 * 136];
  const int lane = threadIdx.x & 63, wave = threadIdx.x >> 6;
  const int t = wave >> 1, ch = wave & 1, cofs = ch * 64;
  const int r0 = blockIdx.x * 32 + t * 16;
  const int lm = lane & 15, lq = lane >> 4;
  f32x4_t acc[4];
  #pragma unroll
  for (int i = 0; i < 4; i++) acc[i] = (f32x4_t){0.f, 0.f, 0.f, 0.f};
  if (*flag){
    const float* arow = (const float*)obj_raw + (size_t)(r0 + lm) * 128 + lq * 8;
    #pragma unroll
    for (int ks = 0; ks < 4; ks++){
      float4 fa = *(const float4*)(arow + ks * 32);
      float4 fb = *(const float4*)(arow + ks * 32 + 4);
      bf16x8_t a;
      a[0] = (short)f2bf(fa.x); a[1] = (short)f2bf(fa.y);
      a[2] = (short)f2bf(fa.z); a[3] = (short)f2bf(fa.w);
      a[4] = (short)f2bf(fb.x); a[5] = (short)f2bf(fb.y);
      a[6] = (short)f2bf(fb.z); a[7] = (short)f2bf(fb.w);
      #pragma unroll
      for (int nb = 0; nb < 4; nb++){
        bf16x8_t bfr = *(const bf16x8_t*)(Wt + (cofs + nb * 16 + lm) * 128 + ks * 32 + lq * 8);
        acc[nb] = __builtin_amdgcn_mfma_f32_16x16x32_bf16(a, bfr, acc[nb], 0, 0, 0);
      }
    }
  } else {
    gemm_tile4((const u16*)obj_raw + (size_t)(r0 + lm) * 128 + lq * 8, Wt, lm, lq, cofs, acc);
  }
  #pragma unroll
  for (int nb = 0; nb < 4; nb++){
    int col = cofs + nb * 16 + lm;
    float bb = biasf[col];
    #pragma unroll
    for (int i = 0; i < 4; i++)
      lds[t][(lq * 4 + i) * 136 + col] = f2bf(fast_tanh(acc[nb][i] + bb));
  }
  __syncthreads();
  phase2_awlaw4(&lds[t][0], Wt, biasf, lm, lq, cofs, r0, awsa, ch ? gat1 : gat0);
}

// mid: states = tanh(sa + lg@Wl + b); then aW/EL/S for next iter.
__global__ void __launch_bounds__(256) fused_mid(const u32* __restrict__ lgsa,
    const u16* __restrict__ Wt, const float* __restrict__ biasf,
    float* __restrict__ awsa, u32* __restrict__ gat0, u32* __restrict__ gat1){
  __shared__ u16 lds[2][16 * 136];
  const int lane = threadIdx.x & 63, wave = threadIdx.x >> 6;
  const int t = wave >> 1, ch = wave & 1, cofs = ch * 64;
  const int r0 = blockIdx.x * 32 + t * 16;
  const int lm = lane & 15, lq = lane >> 4;
  f32x4_t acc[4];
  #pragma unroll
  for (int i = 0; i < 4; i++) acc[i] = (f32x4_t){0.f, 0.f, 0.f, 0.f};
  gemm_tile4_packed(lgsa + (size_t)(r0 + lm) * 128, Wt + 49152, lm, lq, cofs, acc);
  #pragma unroll
  for (int nb = 0; nb < 4; nb++){
    int col = cofs + nb * 16 + lm;
    float bb = biasf[col];
    #pragma unroll
    for (int i = 0; i < 4; i++){
      int row = r0 + lq * 4 + i;
      u32 v = lgsa[(size_t)row * 128 + col];
      u16 hb = (u16)(v >> 16);
      float sa = (float)(*(const _Float16*)&hb);
      lds[t][(lq * 4 + i) * 136 + col] = f2bf(fast_tanh(sa + acc[nb][i] + bb));
    }
  }
  __syncthreads();
  phase2_awlaw4(&lds[t][0], Wt, biasf, lm, lq, cofs, r0, awsa, ch ? gat1 : gat0);
}

// final: out = tanh(sa + lg@Wl + b), fp32 or bf16 per flag.
__global__ void __launch_bounds__(256) final_out(const u32* __restrict__ lgsa,
    const u16* __restrict__ Wt, const float* __restrict__ biasf,
    const int* __restrict__ flag, void* __restrict__ outp){
  const int lane = threadIdx.x & 63, wave = threadIdx.x >> 6;
  const int t = wave >> 1, ch = wave & 1, cofs = ch * 64;
  const int r0 = blockIdx.x * 32 + t * 16;
  const int lm = lane & 15, lq = lane >> 4;
  bool f32out = (*flag != 0);
  f32x4_t acc[4];
  #pragma unroll
  for (int i = 0; i < 4; i++) acc[i] = (f32x4_t){0.f, 0.f, 0.f, 0.f};
  gemm_tile4_packed(lgsa + (size_t)(r0 + lm) * 128, Wt + 49152, lm, lq, cofs, acc);
  #pragma unroll
  for (int nb = 0; nb < 4; nb++){
    int col = cofs + nb * 16 + lm;
    float bb = biasf[col];
    #pragma unroll
    for (int i = 0; i < 4; i++){
      int row = r0 + lq * 4 + i;
      u32 vv = lgsa[(size_t)row * 128 + col];
      u16 hb = (u16)(vv >> 16);
      float sa = (float)(*(const _Float16*)&hb);
      float v = fast_tanh(sa + acc[nb][i] + bb);
      if (f32out) ((float*)outp)[(size_t)row * 128 + col] = v;
      else        ((u16*)  outp)[(size_t)row * 128 + col] = f2bf(v);
    }
  }
}

// ---------------- edge gather: half-channel split, 1 wave/node ----------------
__device__ __forceinline__ void acc_e(u32 g, float& s1, float& s2){
  float el = __uint_as_float(g << 16);
  float sv = __uint_as_float(g & 0xffff0000u);
  s1 += el;
  s2 = fmaf(el, sv, s2);
}

__global__ void __launch_bounds__(256) edge_kernel(const float* __restrict__ awsa,
    const u32* __restrict__ gat0, const u32* __restrict__ gat1,
    const int* __restrict__ row_start, const int* __restrict__ edge_dst,
    u32* __restrict__ lgsa){
  int blk = blockIdx.x;
  int xcd = blk & 7;
  int b = xcd >> 1, h = xcd & 1;
  int i = blk >> 3;                          // 0..2499
  int n = i * 4 + (int)(threadIdx.x >> 6);
  int node = b * NNODE + n;
  int c = threadIdx.x & 63;
  const u32* gh = (h ? gat1 : gat0) + (size_t)b * NNODE * 64;
  int e0 = __builtin_amdgcn_readfirstlane(row_start[b * (NNODE + 1) + n]);
  int e1 = __builtin_amdgcn_readfirstlane(row_start[b * (NNODE + 1) + n + 1]);
  const int* ed = edge_dst + (size_t)b * TWOE;

  float aw = awsa[(size_t)node * 128 + h * 64 + c];
  float ea = __expf(aw);
  float s1 = 0.f, s2 = 0.f, t1 = 0.f, t2 = 0.f;
  int e = e0;
  for (; e + 8 <= e1; e += 8){
    int d0 = ed[e+0], d1 = ed[e+1], d2 = ed[e+2], d3 = ed[e+3];
    int d4 = ed[e+4], d5 = ed[e+5], d6 = ed[e+6], d7 = ed[e+7];
    u32 g0 = gh[(size_t)d0 * 64 + c];
    u32 g1 = gh[(size_t)d1 * 64 + c];
    u32 g2 = gh[(size_t)d2 * 64 + c];
    u32 g3 = gh[(size_t)d3 * 64 + c];
    u32 g4 = gh[(size_t)d4 * 64 + c];
    u32 g5 = gh[(size_t)d5 * 64 + c];
    u32 g6 = gh[(size_t)d6 * 64 + c];
    u32 g7 = gh[(size_t)d7 * 64 + c];
    acc_e(g0, s1, s2); acc_e(g1, t1, t2);
    acc_e(g2, s1, s2); acc_e(g3, t1, t2);
    acc_e(g4, s1, s2); acc_e(g5, t1, t2);
    acc_e(g6, s1, s2); acc_e(g7, t1, t2);
  }
  for (; e < e1; e++){
    u32 gg = gh[(size_t)ed[e] * 64 + c];
    acc_e(gg, s1, s2);
  }
  s1 += t1; s2 += t2;
  float inv = __builtin_amdgcn_rcpf(fmaf(ea, s1, 1.0f));
  float lg = ea * s2 * inv;
  u32 self = gh[(size_t)n * 64 + c];
  float s_self = __uint_as_float(self & 0xffff0000u);
  _Float16 hs = (_Float16)(s_self * inv);
  u32 pk = (u32)f2bf(lg) | ((u32)(*(const u16*)&hs) << 16);
  lgsa[(size_t)node * 128 + h * 64 + c] = pk;
}

// ---------------- host launcher ----------------------------------------------
extern "C" void kernel_launch(void* const* d_in, const int* in_sizes, int n_in,
                              void* d_out, int out_size, void* d_ws, size_t ws_size,
                              hipStream_t stream){
  (void)in_sizes; (void)n_in; (void)ws_size; (void)out_size;
  const void* objects = d_in[0];
  const void* Wo      = d_in[1];
  const void* Wa      = d_in[2];
  const void* Wla     = d_in[3];
  const void* attn_b  = d_in[4];
  const void* Wl      = d_in[5];
  const void* state_b = d_in[6];
  const int*  conn    = (const int*)d_in[7];

  char* base = (char*)d_ws;
  size_t off = 0;
  auto alloc = [&](size_t bytes) -> char* {
    char* p = base + off;
    off = (off + bytes + 255) & ~(size_t)255;
    return p;
  };
  int*   flag      = (int*)  alloc(256);
  u16*   Wt        = (u16*)  alloc((size_t)4 * 16384 * 2);
  float* biasf     = (float*)alloc(256 * 4);
  float* awsa      = (float*)alloc((size_t)MROWS * 128 * 4);   // aW fp32
  u32*   gat0      = (u32*)  alloc((size_t)MROWS * 64 * 4);    // ch 0-63 {EL|S}
  u32*   gat1      = (u32*)  alloc((size_t)MROWS * 64 * 4);    // ch 64-127
  u32*   lgsa      = (u32*)  alloc((size_t)MROWS * 128 * 4);   // {lg bf16 | sa fp16}
  u16*   partial   = (u16*)  alloc((size_t)BATCH * NCHUNK * PADN * 2);
  int*   row_start = (int*)  alloc((size_t)BATCH * (NNODE + 1) * 4);
  int*   edge_dst  = (int*)  alloc((size_t)BATCH * TWOE * 4);
  int*   bsum      = (int*)  alloc(160 * 4);
  int*   boff      = (int*)  alloc(160 * 4);

  detect_dtype<<<1, 256, 0, stream>>>((const u32*)objects, flag);
  prep_weights<<<257, 256, 0, stream>>>(Wo, Wa, Wla, Wl, attn_b, state_b, flag, Wt, biasf);

  csr_hist<<<256, 256, 0, stream>>>(conn, partial);
  csr_colscan<<<160, 256, 0, stream>>>(partial, row_start, bsum);
  scanB<<<1, 256, 0, stream>>>(bsum, boff, row_start);
  scanC<<<160, 256, 0, stream>>>(row_start, boff);
  csr_fill<<<256, 256, 0, stream>>>(conn, partial, row_start, edge_dst);

  fused_init<<<MROWS / 32, 256, 0, stream>>>(objects, flag, Wt, biasf, awsa, gat0, gat1);
  edge_kernel<<<MROWS / 2, 256, 0, stream>>>(awsa, gat0, gat1, row_start, edge_dst, lgsa);
  fused_mid<<<MROWS / 32, 256, 0, stream>>>(lgsa, Wt, biasf, awsa, gat0, gat1);
  edge_kernel<<<MROWS / 2, 256, 0, stream>>>(awsa, gat0, gat1, row_start, edge_dst, lgsa);
  fused_mid<<<MROWS / 32, 256, 0, stream>>>(lgsa, Wt, biasf, awsa, gat0, gat1);
  edge_kernel<<<MROWS / 2, 256, 0, stream>>>(awsa, gat0, gat1, row_start, edge_dst, lgsa);
  final_out<<<MROWS / 32, 256, 0, stream>>>(lgsa, Wt, biasf, flag, d_out);
}

// Round 9
// 405.655 us; speedup vs baseline: 1.8168x; 1.0145x over previous
//
#include <hip/hip_runtime.h>
#include <hip/hip_bf16.h>

// AttentiveGraph: B=4, N=10000, E=160000, C=F=128, 3 iterations.
// R9: byte-diet + XCD locality for the fused GEMMs (R7/R8 showed them pinned
// at ~62MB / 1.2TB/s regardless of occupancy — fabric/LLC wall, not waves):
//  (a) awsa fp32 -> eah fp16 = exp(aW) (clamped 6e4; edge kernel drops exp),
//      write 20.5 -> 10.2 MB per fused dispatch.
//  (b) fused GEMM + final kernels batch-pinned to XCD pairs (blk&7 swizzle,
//      313 sub-blocks of 32 rows/batch + tail guard) so gat/eah writes land
//      in the L2 the pinned edge kernel reads, and lgsa round-trips stay on
//      the pair. CSR (R7 3-phase) + edge kernel structure unchanged.

#define BATCH 4
#define NNODE 10000
#define NEDGE 160000
#define TWOE  (2*NEDGE)
#define MROWS (BATCH*NNODE)   // 40000
#define NCHUNK 64
#define CHUNKE (NEDGE/NCHUNK) // 2500
#define PADN  10240

typedef unsigned short u16;
typedef unsigned int   u32;
typedef __attribute__((ext_vector_type(8))) short bf16x8_t;
typedef __attribute__((ext_vector_type(4))) float f32x4_t;

__device__ __forceinline__ float b2f(u16 h){ return __uint_as_float(((u32)h) << 16); }
__device__ __forceinline__ u16 f2bf(float f){
  u32 u = __float_as_uint(f);
  return (u16)((u + 0x7fffu + ((u >> 16) & 1u)) >> 16);   // RNE
}
__device__ __forceinline__ float fast_tanh(float x){
  float e = __expf(2.0f * x);
  return fmaf(-2.0f, __builtin_amdgcn_rcpf(e + 1.0f), 1.0f);
}

// ---------------- storage dtype probe (fp32 vs bf16 storage) ------------------
__global__ void detect_dtype(const u32* __restrict__ objw, int* __restrict__ flag){
  __shared__ int zc, hc;
  if (threadIdx.x == 0){ zc = 0; hc = 0; }
  __syncthreads();
  int z = 0, h = 0;
  for (int i = threadIdx.x; i < 1024; i += 256){
    u32 lo = objw[i] & 0xffffu;
    if (lo == 0) z++;
    if (((lo >> 7) & 0xffu) >= 160u) h++;
  }
  atomicAdd(&zc, z); atomicAdd(&hc, h);
  __syncthreads();
  if (threadIdx.x == 0) *flag = (hc > 0 || zc > 512) ? 1 : 0;   // 1 = fp32 storage
}

// Wt[m][c*128+k] = W_m[k*128+c]; tail block converts biases.
__global__ void prep_weights(const void* __restrict__ Wo, const void* __restrict__ Wa,
                             const void* __restrict__ Wla, const void* __restrict__ Wl,
                             const void* __restrict__ ab, const void* __restrict__ sb,
                             const int* __restrict__ flag, u16* __restrict__ Wt,
                             float* __restrict__ biasf){
  int idx = blockIdx.x * 256 + threadIdx.x;
  bool f = (*flag != 0);
  if (idx < 65536){
    int m = idx >> 14, k = (idx >> 7) & 127, c = idx & 127;
    const void* src = (m == 0) ? Wo : (m == 1) ? Wa : (m == 2) ? Wla : Wl;
    u16 h = f ? f2bf(((const float*)src)[k * 128 + c]) : ((const u16*)src)[k * 128 + c];
    Wt[m * 16384 + c * 128 + k] = h;
  } else {
    int t = idx - 65536;
    const void* src = (t < 128) ? sb : ab;
    int i = t & 127;
    biasf[t] = f ? ((const float*)src)[i] : b2f(((const u16*)src)[i]);
  }
}

// ---------------- CSR build: 3-phase chunked histogram ------------------------
__device__ __forceinline__ void chunk_of(int blk, int& b, int& c){
  int xcd = blk & 7;
  b = xcd >> 1;
  c = ((blk >> 3) << 1) | (xcd & 1);           // 0..63
}

__global__ void __launch_bounds__(256) csr_hist(const int* __restrict__ conn,
                                                u16* __restrict__ partial){
  int b, c; chunk_of(blockIdx.x, b, c);
  __shared__ u32 hist[NNODE];
  for (int n = threadIdx.x; n < NNODE; n += 256) hist[n] = 0;
  __syncthreads();
  const int2* cp = (const int2*)conn + (size_t)b * NEDGE + c * CHUNKE;
  for (int i = threadIdx.x; i < CHUNKE; i += 256){
    int2 e = cp[i];
    atomicAdd(&hist[e.x], 1);
    atomicAdd(&hist[e.y], 1);
  }
  __syncthreads();
  u16* prow = partial + (size_t)(b * NCHUNK + c) * PADN;
  for (int n = threadIdx.x; n < NNODE; n += 256) prow[n] = (u16)hist[n];
}

__global__ void __launch_bounds__(256) csr_colscan(u16* __restrict__ partial,
    int* __restrict__ row_start, int* __restrict__ bsum){
  int b = blockIdx.x / 40, w = blockIdx.x % 40;
  int n = w * 256 + threadIdx.x;
  u32 run = 0;
  if (n < NNODE){
    #pragma unroll 8
    for (int c = 0; c < NCHUNK; c++){
      size_t idx = (size_t)(b * NCHUNK + c) * PADN + n;
      u32 v = partial[idx];
      partial[idx] = (u16)run;
      run += v;
    }
  }
  __shared__ u32 buf[256];
  buf[threadIdx.x] = run;
  __syncthreads();
  for (int off = 1; off < 256; off <<= 1){
    u32 x = (threadIdx.x >= (unsigned)off) ? buf[threadIdx.x - off] : 0;
    __syncthreads();
    buf[threadIdx.x] += x;
    __syncthreads();
  }
  u32 incl = buf[threadIdx.x];
  if (n < NNODE) row_start[b * (NNODE + 1) + n] = (int)(incl - run);  // window-local
  if (threadIdx.x == 255) bsum[blockIdx.x] = (int)incl;
}

__global__ void scanB(const int* __restrict__ bsum, int* __restrict__ boff,
                      int* __restrict__ row_start){
  __shared__ int s[160];
  if (threadIdx.x < 160) s[threadIdx.x] = bsum[threadIdx.x];
  __syncthreads();
  if (threadIdx.x < 160){
    int b = threadIdx.x / 40, j = threadIdx.x % 40;
    int off = 0;
    for (int q = b * 40; q < b * 40 + j; q++) off += s[q];
    boff[threadIdx.x] = off;
  }
  if (threadIdx.x < BATCH) row_start[threadIdx.x * (NNODE + 1) + NNODE] = TWOE;
}

__global__ void scanC(int* __restrict__ row_start, const int* __restrict__ boff){
  int b = blockIdx.x / 40, j = blockIdx.x % 40;
  int n = j * 256 + threadIdx.x;
  if (n < NNODE) row_start[b * (NNODE + 1) + n] += boff[blockIdx.x];
}

__global__ void __launch_bounds__(256) csr_fill(const int* __restrict__ conn,
    const u16* __restrict__ partial, const int* __restrict__ row_start,
    int* __restrict__ edge_dst){
  int b, c; chunk_of(blockIdx.x, b, c);
  __shared__ u32 cur[NNODE];
  const u16* prow = partial + (size_t)(b * NCHUNK + c) * PADN;
  const int* rs = row_start + b * (NNODE + 1);
  for (int n = threadIdx.x; n < NNODE; n += 256) cur[n] = (u32)rs[n] + prow[n];
  __syncthreads();
  const int2* cp = (const int2*)conn + (size_t)b * NEDGE + c * CHUNKE;
  int* edb = edge_dst + (size_t)b * TWOE;
  for (int i = threadIdx.x; i < CHUNKE; i += 256){
    int2 e = cp[i];
    u32 p1 = atomicAdd(&cur[e.x], 1); edb[p1] = e.y;
    u32 p2 = atomicAdd(&cur[e.y], 1); edb[p2] = e.x;
  }
}

// ---------------- MFMA helpers (wave = 16 rows x 64 cols) ---------------------
__device__ __forceinline__ void gemm_tile4(const u16* __restrict__ arow,
    const u16* __restrict__ wt, int lm, int lq, int cofs, f32x4_t acc[4]){
  #pragma unroll
  for (int ks = 0; ks < 4; ks++){
    bf16x8_t a = *(const bf16x8_t*)(arow + ks * 32);
    #pragma unroll
    for (int nb = 0; nb < 4; nb++){
      bf16x8_t bfr = *(const bf16x8_t*)(wt + (cofs + nb * 16 + lm) * 128 + ks * 32 + lq * 8);
      acc[nb] = __builtin_amdgcn_mfma_f32_16x16x32_bf16(a, bfr, acc[nb], 0, 0, 0);
    }
  }
}

// A-frag from packed lgsa (lg = low u16 of each u32). Lrow = row base ONLY.
__device__ __forceinline__ void gemm_tile4_packed(const u32* __restrict__ Lrow,
    const u16* __restrict__ wt, int lm, int lq, int cofs, f32x4_t acc[4]){
  #pragma unroll
  for (int ks = 0; ks < 4; ks++){
    uint4 wa = *(const uint4*)(Lrow + ks * 32 + lq * 8);
    uint4 wb = *(const uint4*)(Lrow + ks * 32 + lq * 8 + 4);
    bf16x8_t a;
    a[0] = (short)wa.x; a[1] = (short)wa.y; a[2] = (short)wa.z; a[3] = (short)wa.w;
    a[4] = (short)wb.x; a[5] = (short)wb.y; a[6] = (short)wb.z; a[7] = (short)wb.w;
    #pragma unroll
    for (int nb = 0; nb < 4; nb++){
      bf16x8_t bfr = *(const bf16x8_t*)(wt + (cofs + nb * 16 + lm) * 128 + ks * 32 + lq * 8);
      acc[nb] = __builtin_amdgcn_mfma_f32_16x16x32_bf16(a, bfr, acc[nb], 0, 0, 0);
    }
  }
}

// phase 2: states tile (LDS, A-layout) -> eah fp16 = clamped exp(aW), and
// single-u32 {EL|S} gat store. gr0 = global row base (b*NNODE + batch row).
__device__ __forceinline__ void phase2_awlaw4(const u16* __restrict__ ldstile,
    const u16* __restrict__ Wt, const float* __restrict__ biasf,
    int lm, int lq, int cofs, int gr0, _Float16* __restrict__ eah,
    u32* __restrict__ ghw){
  const u16* Wta  = Wt + 16384;
  const u16* Wtla = Wt + 32768;
  const u16* ldsrow = ldstile + lm * 136 + lq * 8;
  f32x4_t accA[4], accL[4];
  #pragma unroll
  for (int i = 0; i < 4; i++){ accA[i] = (f32x4_t){0.f,0.f,0.f,0.f}; accL[i] = (f32x4_t){0.f,0.f,0.f,0.f}; }
  #pragma unroll
  for (int ks = 0; ks < 4; ks++){
    bf16x8_t a = *(const bf16x8_t*)(ldsrow + ks * 32);
    #pragma unroll
    for (int nb = 0; nb < 4; nb++){
      bf16x8_t ba = *(const bf16x8_t*)(Wta  + (cofs + nb * 16 + lm) * 128 + ks * 32 + lq * 8);
      bf16x8_t bl = *(const bf16x8_t*)(Wtla + (cofs + nb * 16 + lm) * 128 + ks * 32 + lq * 8);
      accA[nb] = __builtin_amdgcn_mfma_f32_16x16x32_bf16(a, ba, accA[nb], 0, 0, 0);
      accL[nb] = __builtin_amdgcn_mfma_f32_16x16x32_bf16(a, bl, accL[nb], 0, 0, 0);
    }
  }
  #pragma unroll
  for (int nb = 0; nb < 4; nb++){
    int col = cofs + nb * 16 + lm;
    float bb = biasf[128 + col];
    #pragma unroll
    for (int i = 0; i < 4; i++){
      int row = gr0 + lq * 4 + i;
      float ea = fminf(__expf(accA[nb][i]), 60000.0f);   // fp16-safe; exact in the ea>>1 limit
      eah[(size_t)row * 128 + col] = (_Float16)ea;
      u16 el = f2bf(__expf(accL[nb][i] + bb));
      u16 s  = ldstile[(lq * 4 + i) * 136 + col];
      ghw[(size_t)row * 64 + (col & 63)] = (u32)el | ((u32)s << 16);
    }
  }
}

// batch-pinned sub-block decode for fused kernels: xcd=blk&7 -> batch=xcd>>1,
// sub=((blk>>3)<<1)|(xcd&1) in 0..313 (313 x 32-row sub-blocks per batch).
__device__ __forceinline__ bool fused_decode(int blk, int wave, int& b, int& r0,
                                             int& t, int& ch, bool& valid){
  int xcd = blk & 7;
  b = xcd >> 1;
  int sub = ((blk >> 3) << 1) | (xcd & 1);
  t = wave >> 1; ch = wave & 1;
  r0 = sub * 32 + t * 16;                      // batch-local row base
  valid = (sub < 313) && (r0 < NNODE);         // tail: sub=312,t=1 invalid
  if (!valid) r0 = 0;                          // clamp loads in-bounds
  return sub < 313;                            // false -> whole block idle
}

// init: states = tanh(obj@Wo + b) from raw objects; then eah/EL/S.
__global__ void __launch_bounds__(256) fused_init(const void* __restrict__ obj_raw,
    const int* __restrict__ flag, const u16* __restrict__ Wt,
    const float* __restrict__ biasf, _Float16* __restrict__ eah,
    u32* __restrict__ gat0, u32* __restrict__ gat1){
  __shared__ u16 lds[2][16 * 136];
  const int lane = threadIdx.x & 63, wave = threadIdx.x >> 6;
  int b, r0, t, ch; bool valid;
  if (!fused_decode(blockIdx.x, wave, b, r0, t, ch, valid)) return;
  const int cofs = ch * 64;
  const int lm = lane & 15, lq = lane >> 4;
  const int gr0 = b * NNODE + r0;
  f32x4_t acc[4];
  #pragma unroll
  for (int i = 0; i < 4; i++) acc[i] = (f32x4_t){0.f, 0.f, 0.f, 0.f};
  if (*flag){
    const float* arow = (const float*)obj_raw + (size_t)(gr0 + lm) * 128 + lq * 8;
    #pragma unroll
    for (int ks = 0; ks < 4; ks++){
      float4 fa = *(const float4*)(arow + ks * 32);
      float4 fb = *(const float4*)(arow + ks * 32 + 4);
      bf16x8_t a;
      a[0] = (short)f2bf(fa.x); a[1] = (short)f2bf(fa.y);
      a[2] = (short)f2bf(fa.z); a[3] = (short)f2bf(fa.w);
      a[4] = (short)f2bf(fb.x); a[5] = (short)f2bf(fb.y);
      a[6] = (short)f2bf(fb.z); a[7] = (short)f2bf(fb.w);
      #pragma unroll
      for (int nb = 0; nb < 4; nb++){
        bf16x8_t bfr = *(const bf16x8_t*)(Wt + (cofs + nb * 16 + lm) * 128 + ks * 32 + lq * 8);
        acc[nb] = __builtin_amdgcn_mfma_f32_16x16x32_bf16(a, bfr, acc[nb], 0, 0, 0);
      }
    }
  } else {
    gemm_tile4((const u16*)obj_raw + (size_t)(gr0 + lm) * 128 + lq * 8, Wt, lm, lq, cofs, acc);
  }
  #pragma unroll
  for (int nb = 0; nb < 4; nb++){
    int col = cofs + nb * 16 + lm;
    float bb = biasf[col];
    #pragma unroll
    for (int i = 0; i < 4; i++)
      lds[t][(lq * 4 + i) * 136 + col] = f2bf(fast_tanh(acc[nb][i] + bb));
  }
  __syncthreads();
  if (valid)
    phase2_awlaw4(&lds[t][0], Wt, biasf, lm, lq, cofs, gr0, eah, ch ? gat1 : gat0);
}

// mid: states = tanh(sa + lg@Wl + b); then eah/EL/S for next iter.
__global__ void __launch_bounds__(256) fused_mid(const u32* __restrict__ lgsa,
    const u16* __restrict__ Wt, const float* __restrict__ biasf,
    _Float16* __restrict__ eah, u32* __restrict__ gat0, u32* __restrict__ gat1){
  __shared__ u16 lds[2][16 * 136];
  const int lane = threadIdx.x & 63, wave = threadIdx.x >> 6;
  int b, r0, t, ch; bool valid;
  if (!fused_decode(blockIdx.x, wave, b, r0, t, ch, valid)) return;
  const int cofs = ch * 64;
  const int lm = lane & 15, lq = lane >> 4;
  const int gr0 = b * NNODE + r0;
  f32x4_t acc[4];
  #pragma unroll
  for (int i = 0; i < 4; i++) acc[i] = (f32x4_t){0.f, 0.f, 0.f, 0.f};
  gemm_tile4_packed(lgsa + (size_t)(gr0 + lm) * 128, Wt + 49152, lm, lq, cofs, acc);
  #pragma unroll
  for (int nb = 0; nb < 4; nb++){
    int col = cofs + nb * 16 + lm;
    float bb = biasf[col];
    #pragma unroll
    for (int i = 0; i < 4; i++){
      int row = gr0 + lq * 4 + i;
      u32 v = lgsa[(size_t)row * 128 + col];
      u16 hb = (u16)(v >> 16);
      float sa = (float)(*(const _Float16*)&hb);
      lds[t][(lq * 4 + i) * 136 + col] = f2bf(fast_tanh(sa + acc[nb][i] + bb));
    }
  }
  __syncthreads();
  if (valid)
    phase2_awlaw4(&lds[t][0], Wt, biasf, lm, lq, cofs, gr0, eah, ch ? gat1 : gat0);
}

// final: out = tanh(sa + lg@Wl + b), fp32 or bf16 per flag.
__global__ void __launch_bounds__(256) final_out(const u32* __restrict__ lgsa,
    const u16* __restrict__ Wt, const float* __restrict__ biasf,
    const int* __restrict__ flag, void* __restrict__ outp){
  const int lane = threadIdx.x & 63, wave = threadIdx.x >> 6;
  int b, r0, t, ch; bool valid;
  if (!fused_decode(blockIdx.x, wave, b, r0, t, ch, valid)) return;
  const int cofs = ch * 64;
  const int lm = lane & 15, lq = lane >> 4;
  const int gr0 = b * NNODE + r0;
  bool f32out = (*flag != 0);
  f32x4_t acc[4];
  #pragma unroll
  for (int i = 0; i < 4; i++) acc[i] = (f32x4_t){0.f, 0.f, 0.f, 0.f};
  gemm_tile4_packed(lgsa + (size_t)(gr0 + lm) * 128, Wt + 49152, lm, lq, cofs, acc);
  if (!valid) return;
  #pragma unroll
  for (int nb = 0; nb < 4; nb++){
    int col = cofs + nb * 16 + lm;
    float bb = biasf[col];
    #pragma unroll
    for (int i = 0; i < 4; i++){
      int row = gr0 + lq * 4 + i;
      u32 vv = lgsa[(size_t)row * 128 + col];
      u16 hb = (u16)(vv >> 16);
      float sa = (float)(*(const _Float16*)&hb);
      float v = fast_tanh(sa + acc[nb][i] + bb);
      if (f32out) ((float*)outp)[(size_t)row * 128 + col] = v;
      else        ((u16*)  outp)[(size_t)row * 128 + col] = f2bf(v);
    }
  }
}

// ---------------- edge gather: half-channel split, 1 wave/node ----------------
__device__ __forceinline__ void acc_e(u32 g, float& s1, float& s2){
  float el = __uint_as_float(g << 16);
  float sv = __uint_as_float(g & 0xffff0000u);
  s1 += el;
  s2 = fmaf(el, sv, s2);
}

__global__ void __launch_bounds__(256) edge_kernel(const _Float16* __restrict__ eah,
    const u32* __restrict__ gat0, const u32* __restrict__ gat1,
    const int* __restrict__ row_start, const int* __restrict__ edge_dst,
    u32* __restrict__ lgsa){
  int blk = blockIdx.x;
  int xcd = blk & 7;
  int b = xcd >> 1, h = xcd & 1;
  int i = blk >> 3;                          // 0..2499
  int n = i * 4 + (int)(threadIdx.x >> 6);
  int node = b * NNODE + n;
  int c = threadIdx.x & 63;
  const u32* gh = (h ? gat1 : gat0) + (size_t)b * NNODE * 64;
  int e0 = __builtin_amdgcn_readfirstlane(row_start[b * (NNODE + 1) + n]);
  int e1 = __builtin_amdgcn_readfirstlane(row_start[b * (NNODE + 1) + n + 1]);
  const int* ed = edge_dst + (size_t)b * TWOE;

  float ea = (float)eah[(size_t)node * 128 + h * 64 + c];
  float s1 = 0.f, s2 = 0.f, t1 = 0.f, t2 = 0.f;
  int e = e0;
  for (; e + 8 <= e1; e += 8){
    int d0 = ed[e+0], d1 = ed[e+1], d2 = ed[e+2], d3 = ed[e+3];
    int d4 = ed[e+4], d5 = ed[e+5], d6 = ed[e+6], d7 = ed[e+7];
    u32 g0 = gh[(size_t)d0 * 64 + c];
    u32 g1 = gh[(size_t)d1 * 64 + c];
    u32 g2 = gh[(size_t)d2 * 64 + c];
    u32 g3 = gh[(size_t)d3 * 64 + c];
    u32 g4 = gh[(size_t)d4 * 64 + c];
    u32 g5 = gh[(size_t)d5 * 64 + c];
    u32 g6 = gh[(size_t)d6 * 64 + c];
    u32 g7 = gh[(size_t)d7 * 64 + c];
    acc_e(g0, s1, s2); acc_e(g1, t1, t2);
    acc_e(g2, s1, s2); acc_e(g3, t1, t2);
    acc_e(g4, s1, s2); acc_e(g5, t1, t2);
    acc_e(g6, s1, s2); acc_e(g7, t1, t2);
  }
  for (; e < e1; e++){
    u32 gg = gh[(size_t)ed[e] * 64 + c];
    acc_e(gg, s1, s2);
  }
  s1 += t1; s2 += t2;
  float inv = __builtin_amdgcn_rcpf(fmaf(ea, s1, 1.0f));
  float lg = ea * s2 * inv;
  u32 self = gh[(size_t)n * 64 + c];
  float s_self = __uint_as_float(self & 0xffff0000u);
  _Float16 hs = (_Float16)(s_self * inv);
  u32 pk = (u32)f2bf(lg) | ((u32)(*(const u16*)&hs) << 16);
  lgsa[(size_t)node * 128 + h * 64 + c] = pk;
}

// ---------------- host launcher ----------------------------------------------
extern "C" void kernel_launch(void* const* d_in, const int* in_sizes, int n_in,
                              void* d_out, int out_size, void* d_ws, size_t ws_size,
                              hipStream_t stream){
  (void)in_sizes; (void)n_in; (void)ws_size; (void)out_size;
  const void* objects = d_in[0];
  const void* Wo      = d_in[1];
  const void* Wa      = d_in[2];
  const void* Wla     = d_in[3];
  const void* attn_b  = d_in[4];
  const void* Wl      = d_in[5];
  const void* state_b = d_in[6];
  const int*  conn    = (const int*)d_in[7];

  char* base = (char*)d_ws;
  size_t off = 0;
  auto alloc = [&](size_t bytes) -> char* {
    char* p = base + off;
    off = (off + bytes + 255) & ~(size_t)255;
    return p;
  };
  int*      flag      = (int*)     alloc(256);
  u16*      Wt        = (u16*)     alloc((size_t)4 * 16384 * 2);
  float*    biasf     = (float*)   alloc(256 * 4);
  _Float16* eah       = (_Float16*)alloc((size_t)MROWS * 128 * 2);  // exp(aW) fp16
  u32*      gat0      = (u32*)     alloc((size_t)MROWS * 64 * 4);   // ch 0-63 {EL|S}
  u32*      gat1      = (u32*)     alloc((size_t)MROWS * 64 * 4);   // ch 64-127
  u32*      lgsa      = (u32*)     alloc((size_t)MROWS * 128 * 4);  // {lg bf16 | sa fp16}
  u16*      partial   = (u16*)     alloc((size_t)BATCH * NCHUNK * PADN * 2);
  int*      row_start = (int*)     alloc((size_t)BATCH * (NNODE + 1) * 4);
  int*      edge_dst  = (int*)     alloc((size_t)BATCH * TWOE * 4);
  int*      bsum      = (int*)     alloc(160 * 4);
  int*      boff      = (int*)     alloc(160 * 4);

  detect_dtype<<<1, 256, 0, stream>>>((const u32*)objects, flag);
  prep_weights<<<257, 256, 0, stream>>>(Wo, Wa, Wla, Wl, attn_b, state_b, flag, Wt, biasf);

  csr_hist<<<256, 256, 0, stream>>>(conn, partial);
  csr_colscan<<<160, 256, 0, stream>>>(partial, row_start, bsum);
  scanB<<<1, 256, 0, stream>>>(bsum, boff, row_start);
  scanC<<<160, 256, 0, stream>>>(row_start, boff);
  csr_fill<<<256, 256, 0, stream>>>(conn, partial, row_start, edge_dst);

  const int FGRID = 157 * 8;   // 313 x 32-row sub-blocks per batch, XCD-pinned
  fused_init<<<FGRID, 256, 0, stream>>>(objects, flag, Wt, biasf, eah, gat0, gat1);
  edge_kernel<<<MROWS / 2, 256, 0, stream>>>(eah, gat0, gat1, row_start, edge_dst, lgsa);
  fused_mid<<<FGRID, 256, 0, stream>>>(lgsa, Wt, biasf, eah, gat0, gat1);
  edge_kernel<<<MROWS / 2, 256, 0, stream>>>(eah, gat0, gat1, row_start, edge_dst, lgsa);
  fused_mid<<<FGRID, 256, 0, stream>>>(lgsa, Wt, biasf, eah, gat0, gat1);
  edge_kernel<<<MROWS / 2, 256, 0, stream>>>(eah, gat0, gat1, row_start, edge_dst, lgsa);
  final_out<<<FGRID, 256, 0, stream>>>(lgsa, Wt, biasf, flag, d_out);
}

// Round 10
// 388.879 us; speedup vs baseline: 1.8952x; 1.0431x over previous
//
#include <hip/hip_runtime.h>
#include <hip/hip_bf16.h>

// AttentiveGraph: B=4, N=10000, E=160000, C=F=128, 3 iterations.
// R10: (a) fused GEMM kernels un-pinned (R9 pinning: +17us/dispatch at equal
// bytes — peer-L2 dirty-line snoops on full-row lgsa reads); back to R8's
// linear 32-row block mapping. (b) eah fp16 kept but staged through LDS and
// written with 16B/thread coalesced stores (R9's 2B/lane direct stores
// caused ~2x line-fill amplification: WRITE 39.9MB vs expected 31MB).
// CSR (R7 3-phase chunked histogram) + pinned edge kernel unchanged.

#define BATCH 4
#define NNODE 10000
#define NEDGE 160000
#define TWOE  (2*NEDGE)
#define MROWS (BATCH*NNODE)   // 40000
#define NCHUNK 64
#define CHUNKE (NEDGE/NCHUNK) // 2500
#define PADN  10240

typedef unsigned short u16;
typedef unsigned int   u32;
typedef __attribute__((ext_vector_type(8))) short bf16x8_t;
typedef __attribute__((ext_vector_type(4))) float f32x4_t;

__device__ __forceinline__ float b2f(u16 h){ return __uint_as_float(((u32)h) << 16); }
__device__ __forceinline__ u16 f2bf(float f){
  u32 u = __float_as_uint(f);
  return (u16)((u + 0x7fffu + ((u >> 16) & 1u)) >> 16);   // RNE
}
__device__ __forceinline__ float fast_tanh(float x){
  float e = __expf(2.0f * x);
  return fmaf(-2.0f, __builtin_amdgcn_rcpf(e + 1.0f), 1.0f);
}

// ---------------- storage dtype probe (fp32 vs bf16 storage) ------------------
__global__ void detect_dtype(const u32* __restrict__ objw, int* __restrict__ flag){
  __shared__ int zc, hc;
  if (threadIdx.x == 0){ zc = 0; hc = 0; }
  __syncthreads();
  int z = 0, h = 0;
  for (int i = threadIdx.x; i < 1024; i += 256){
    u32 lo = objw[i] & 0xffffu;
    if (lo == 0) z++;
    if (((lo >> 7) & 0xffu) >= 160u) h++;
  }
  atomicAdd(&zc, z); atomicAdd(&hc, h);
  __syncthreads();
  if (threadIdx.x == 0) *flag = (hc > 0 || zc > 512) ? 1 : 0;   // 1 = fp32 storage
}

// Wt[m][c*128+k] = W_m[k*128+c]; tail block converts biases.
__global__ void prep_weights(const void* __restrict__ Wo, const void* __restrict__ Wa,
                             const void* __restrict__ Wla, const void* __restrict__ Wl,
                             const void* __restrict__ ab, const void* __restrict__ sb,
                             const int* __restrict__ flag, u16* __restrict__ Wt,
                             float* __restrict__ biasf){
  int idx = blockIdx.x * 256 + threadIdx.x;
  bool f = (*flag != 0);
  if (idx < 65536){
    int m = idx >> 14, k = (idx >> 7) & 127, c = idx & 127;
    const void* src = (m == 0) ? Wo : (m == 1) ? Wa : (m == 2) ? Wla : Wl;
    u16 h = f ? f2bf(((const float*)src)[k * 128 + c]) : ((const u16*)src)[k * 128 + c];
    Wt[m * 16384 + c * 128 + k] = h;
  } else {
    int t = idx - 65536;
    const void* src = (t < 128) ? sb : ab;
    int i = t & 127;
    biasf[t] = f ? ((const float*)src)[i] : b2f(((const u16*)src)[i]);
  }
}

// ---------------- CSR build: 3-phase chunked histogram ------------------------
__device__ __forceinline__ void chunk_of(int blk, int& b, int& c){
  int xcd = blk & 7;
  b = xcd >> 1;
  c = ((blk >> 3) << 1) | (xcd & 1);           // 0..63
}

__global__ void __launch_bounds__(256) csr_hist(const int* __restrict__ conn,
                                                u16* __restrict__ partial){
  int b, c; chunk_of(blockIdx.x, b, c);
  __shared__ u32 hist[NNODE];
  for (int n = threadIdx.x; n < NNODE; n += 256) hist[n] = 0;
  __syncthreads();
  const int2* cp = (const int2*)conn + (size_t)b * NEDGE + c * CHUNKE;
  for (int i = threadIdx.x; i < CHUNKE; i += 256){
    int2 e = cp[i];
    atomicAdd(&hist[e.x], 1);
    atomicAdd(&hist[e.y], 1);
  }
  __syncthreads();
  u16* prow = partial + (size_t)(b * NCHUNK + c) * PADN;
  for (int n = threadIdx.x; n < NNODE; n += 256) prow[n] = (u16)hist[n];
}

__global__ void __launch_bounds__(256) csr_colscan(u16* __restrict__ partial,
    int* __restrict__ row_start, int* __restrict__ bsum){
  int b = blockIdx.x / 40, w = blockIdx.x % 40;
  int n = w * 256 + threadIdx.x;
  u32 run = 0;
  if (n < NNODE){
    #pragma unroll 8
    for (int c = 0; c < NCHUNK; c++){
      size_t idx = (size_t)(b * NCHUNK + c) * PADN + n;
      u32 v = partial[idx];
      partial[idx] = (u16)run;
      run += v;
    }
  }
  __shared__ u32 buf[256];
  buf[threadIdx.x] = run;
  __syncthreads();
  for (int off = 1; off < 256; off <<= 1){
    u32 x = (threadIdx.x >= (unsigned)off) ? buf[threadIdx.x - off] : 0;
    __syncthreads();
    buf[threadIdx.x] += x;
    __syncthreads();
  }
  u32 incl = buf[threadIdx.x];
  if (n < NNODE) row_start[b * (NNODE + 1) + n] = (int)(incl - run);  // window-local
  if (threadIdx.x == 255) bsum[blockIdx.x] = (int)incl;
}

__global__ void scanB(const int* __restrict__ bsum, int* __restrict__ boff,
                      int* __restrict__ row_start){
  __shared__ int s[160];
  if (threadIdx.x < 160) s[threadIdx.x] = bsum[threadIdx.x];
  __syncthreads();
  if (threadIdx.x < 160){
    int b = threadIdx.x / 40, j = threadIdx.x % 40;
    int off = 0;
    for (int q = b * 40; q < b * 40 + j; q++) off += s[q];
    boff[threadIdx.x] = off;
  }
  if (threadIdx.x < BATCH) row_start[threadIdx.x * (NNODE + 1) + NNODE] = TWOE;
}

__global__ void scanC(int* __restrict__ row_start, const int* __restrict__ boff){
  int b = blockIdx.x / 40, j = blockIdx.x % 40;
  int n = j * 256 + threadIdx.x;
  if (n < NNODE) row_start[b * (NNODE + 1) + n] += boff[blockIdx.x];
}

__global__ void __launch_bounds__(256) csr_fill(const int* __restrict__ conn,
    const u16* __restrict__ partial, const int* __restrict__ row_start,
    int* __restrict__ edge_dst){
  int b, c; chunk_of(blockIdx.x, b, c);
  __shared__ u32 cur[NNODE];
  const u16* prow = partial + (size_t)(b * NCHUNK + c) * PADN;
  const int* rs = row_start + b * (NNODE + 1);
  for (int n = threadIdx.x; n < NNODE; n += 256) cur[n] = (u32)rs[n] + prow[n];
  __syncthreads();
  const int2* cp = (const int2*)conn + (size_t)b * NEDGE + c * CHUNKE;
  int* edb = edge_dst + (size_t)b * TWOE;
  for (int i = threadIdx.x; i < CHUNKE; i += 256){
    int2 e = cp[i];
    u32 p1 = atomicAdd(&cur[e.x], 1); edb[p1] = e.y;
    u32 p2 = atomicAdd(&cur[e.y], 1); edb[p2] = e.x;
  }
}

// ---------------- MFMA helpers (wave = 16 rows x 64 cols) ---------------------
__device__ __forceinline__ void gemm_tile4(const u16* __restrict__ arow,
    const u16* __restrict__ wt, int lm, int lq, int cofs, f32x4_t acc[4]){
  #pragma unroll
  for (int ks = 0; ks < 4; ks++){
    bf16x8_t a = *(const bf16x8_t*)(arow + ks * 32);
    #pragma unroll
    for (int nb = 0; nb < 4; nb++){
      bf16x8_t bfr = *(const bf16x8_t*)(wt + (cofs + nb * 16 + lm) * 128 + ks * 32 + lq * 8);
      acc[nb] = __builtin_amdgcn_mfma_f32_16x16x32_bf16(a, bfr, acc[nb], 0, 0, 0);
    }
  }
}

// A-frag from packed lgsa (lg = low u16 of each u32). Lrow = row base ONLY.
__device__ __forceinline__ void gemm_tile4_packed(const u32* __restrict__ Lrow,
    const u16* __restrict__ wt, int lm, int lq, int cofs, f32x4_t acc[4]){
  #pragma unroll
  for (int ks = 0; ks < 4; ks++){
    uint4 wa = *(const uint4*)(Lrow + ks * 32 + lq * 8);
    uint4 wb = *(const uint4*)(Lrow + ks * 32 + lq * 8 + 4);
    bf16x8_t a;
    a[0] = (short)wa.x; a[1] = (short)wa.y; a[2] = (short)wa.z; a[3] = (short)wa.w;
    a[4] = (short)wb.x; a[5] = (short)wb.y; a[6] = (short)wb.z; a[7] = (short)wb.w;
    #pragma unroll
    for (int nb = 0; nb < 4; nb++){
      bf16x8_t bfr = *(const bf16x8_t*)(wt + (cofs + nb * 16 + lm) * 128 + ks * 32 + lq * 8);
      acc[nb] = __builtin_amdgcn_mfma_f32_16x16x32_bf16(a, bfr, acc[nb], 0, 0, 0);
    }
  }
}

// phase 2: states tile (LDS, A-layout) -> gat {EL|S} u32 stores (full-line) +
// ea fp16 into LDS tile eat (coalesced global store done by caller).
__device__ __forceinline__ void phase2_awlaw4(const u16* __restrict__ ldstile,
    const u16* __restrict__ Wt, const float* __restrict__ biasf,
    int lm, int lq, int cofs, int r0, _Float16* __restrict__ eat,
    u32* __restrict__ ghw){
  const u16* Wta  = Wt + 16384;
  const u16* Wtla = Wt + 32768;
  const u16* ldsrow = ldstile + lm * 136 + lq * 8;
  f32x4_t accA[4], accL[4];
  #pragma unroll
  for (int i = 0; i < 4; i++){ accA[i] = (f32x4_t){0.f,0.f,0.f,0.f}; accL[i] = (f32x4_t){0.f,0.f,0.f,0.f}; }
  #pragma unroll
  for (int ks = 0; ks < 4; ks++){
    bf16x8_t a = *(const bf16x8_t*)(ldsrow + ks * 32);
    #pragma unroll
    for (int nb = 0; nb < 4; nb++){
      bf16x8_t ba = *(const bf16x8_t*)(Wta  + (cofs + nb * 16 + lm) * 128 + ks * 32 + lq * 8);
      bf16x8_t bl = *(const bf16x8_t*)(Wtla + (cofs + nb * 16 + lm) * 128 + ks * 32 + lq * 8);
      accA[nb] = __builtin_amdgcn_mfma_f32_16x16x32_bf16(a, ba, accA[nb], 0, 0, 0);
      accL[nb] = __builtin_amdgcn_mfma_f32_16x16x32_bf16(a, bl, accL[nb], 0, 0, 0);
    }
  }
  #pragma unroll
  for (int nb = 0; nb < 4; nb++){
    int col = cofs + nb * 16 + lm;
    float bb = biasf[128 + col];
    #pragma unroll
    for (int i = 0; i < 4; i++){
      int row = r0 + lq * 4 + i;
      float ea = fminf(__expf(accA[nb][i]), 60000.0f);   // fp16-safe; exact in ea>>1 limit
      eat[(lq * 4 + i) * 128 + col] = (_Float16)ea;
      u16 el = f2bf(__expf(accL[nb][i] + bb));
      u16 s  = ldstile[(lq * 4 + i) * 136 + col];
      ghw[(size_t)row * 64 + (col & 63)] = (u32)el | ((u32)s << 16);
    }
  }
}

// coalesced eah writeback: 2 tiles x 16 rows x 128 fp16 = 8KB, 16B/thread x2.
__device__ __forceinline__ void eah_writeback(const _Float16* __restrict__ eat,
    _Float16* __restrict__ eah, int blk_r0, int tid){
  const uint4* src = (const uint4*)eat;       // 512 x 16B
  uint4* dst = (uint4*)(eah + (size_t)blk_r0 * 128);
  dst[tid]       = src[tid];
  dst[tid + 256] = src[tid + 256];
}

// init: states = tanh(obj@Wo + b) from raw objects; then eah/EL/S.
__global__ void __launch_bounds__(256) fused_init(const void* __restrict__ obj_raw,
    const int* __restrict__ flag, const u16* __restrict__ Wt,
    const float* __restrict__ biasf, _Float16* __restrict__ eah,
    u32* __restrict__ gat0, u32* __restrict__ gat1){
  __shared__ u16 lds[2][16 * 136];
  __shared__ _Float16 eat[2][16 * 128];
  const int lane = threadIdx.x & 63, wave = threadIdx.x >> 6;
  const int t = wave >> 1, ch = wave & 1, cofs = ch * 64;
  const int r0 = blockIdx.x * 32 + t * 16;
  const int lm = lane & 15, lq = lane >> 4;
  f32x4_t acc[4];
  #pragma unroll
  for (int i = 0; i < 4; i++) acc[i] = (f32x4_t){0.f, 0.f, 0.f, 0.f};
  if (*flag){
    const float* arow = (const float*)obj_raw + (size_t)(r0 + lm) * 128 + lq * 8;
    #pragma unroll
    for (int ks = 0; ks < 4; ks++){
      float4 fa = *(const float4*)(arow + ks * 32);
      float4 fb = *(const float4*)(arow + ks * 32 + 4);
      bf16x8_t a;
      a[0] = (short)f2bf(fa.x); a[1] = (short)f2bf(fa.y);
      a[2] = (short)f2bf(fa.z); a[3] = (short)f2bf(fa.w);
      a[4] = (short)f2bf(fb.x); a[5] = (short)f2bf(fb.y);
      a[6] = (short)f2bf(fb.z); a[7] = (short)f2bf(fb.w);
      #pragma unroll
      for (int nb = 0; nb < 4; nb++){
        bf16x8_t bfr = *(const bf16x8_t*)(Wt + (cofs + nb * 16 + lm) * 128 + ks * 32 + lq * 8);
        acc[nb] = __builtin_amdgcn_mfma_f32_16x16x32_bf16(a, bfr, acc[nb], 0, 0, 0);
      }
    }
  } else {
    gemm_tile4((const u16*)obj_raw + (size_t)(r0 + lm) * 128 + lq * 8, Wt, lm, lq, cofs, acc);
  }
  #pragma unroll
  for (int nb = 0; nb < 4; nb++){
    int col = cofs + nb * 16 + lm;
    float bb = biasf[col];
    #pragma unroll
    for (int i = 0; i < 4; i++)
      lds[t][(lq * 4 + i) * 136 + col] = f2bf(fast_tanh(acc[nb][i] + bb));
  }
  __syncthreads();
  phase2_awlaw4(&lds[t][0], Wt, biasf, lm, lq, cofs, r0, &eat[t][0], ch ? gat1 : gat0);
  __syncthreads();
  eah_writeback(&eat[0][0], eah, blockIdx.x * 32, threadIdx.x);
}

// mid: states = tanh(sa + lg@Wl + b); then eah/EL/S for next iter.
__global__ void __launch_bounds__(256) fused_mid(const u32* __restrict__ lgsa,
    const u16* __restrict__ Wt, const float* __restrict__ biasf,
    _Float16* __restrict__ eah, u32* __restrict__ gat0, u32* __restrict__ gat1){
  __shared__ u16 lds[2][16 * 136];
  __shared__ _Float16 eat[2][16 * 128];
  const int lane = threadIdx.x & 63, wave = threadIdx.x >> 6;
  const int t = wave >> 1, ch = wave & 1, cofs = ch * 64;
  const int r0 = blockIdx.x * 32 + t * 16;
  const int lm = lane & 15, lq = lane >> 4;
  f32x4_t acc[4];
  #pragma unroll
  for (int i = 0; i < 4; i++) acc[i] = (f32x4_t){0.f, 0.f, 0.f, 0.f};
  gemm_tile4_packed(lgsa + (size_t)(r0 + lm) * 128, Wt + 49152, lm, lq, cofs, acc);
  #pragma unroll
  for (int nb = 0; nb < 4; nb++){
    int col = cofs + nb * 16 + lm;
    float bb = biasf[col];
    #pragma unroll
    for (int i = 0; i < 4; i++){
      int row = r0 + lq * 4 + i;
      u32 v = lgsa[(size_t)row * 128 + col];
      u16 hb = (u16)(v >> 16);
      float sa = (float)(*(const _Float16*)&hb);
      lds[t][(lq * 4 + i) * 136 + col] = f2bf(fast_tanh(sa + acc[nb][i] + bb));
    }
  }
  __syncthreads();
  phase2_awlaw4(&lds[t][0], Wt, biasf, lm, lq, cofs, r0, &eat[t][0], ch ? gat1 : gat0);
  __syncthreads();
  eah_writeback(&eat[0][0], eah, blockIdx.x * 32, threadIdx.x);
}

// final: out = tanh(sa + lg@Wl + b), fp32 or bf16 per flag.
__global__ void __launch_bounds__(256) final_out(const u32* __restrict__ lgsa,
    const u16* __restrict__ Wt, const float* __restrict__ biasf,
    const int* __restrict__ flag, void* __restrict__ outp){
  const int lane = threadIdx.x & 63, wave = threadIdx.x >> 6;
  const int t = wave >> 1, ch = wave & 1, cofs = ch * 64;
  const int r0 = blockIdx.x * 32 + t * 16;
  const int lm = lane & 15, lq = lane >> 4;
  bool f32out = (*flag != 0);
  f32x4_t acc[4];
  #pragma unroll
  for (int i = 0; i < 4; i++) acc[i] = (f32x4_t){0.f, 0.f, 0.f, 0.f};
  gemm_tile4_packed(lgsa + (size_t)(r0 + lm) * 128, Wt + 49152, lm, lq, cofs, acc);
  #pragma unroll
  for (int nb = 0; nb < 4; nb++){
    int col = cofs + nb * 16 + lm;
    float bb = biasf[col];
    #pragma unroll
    for (int i = 0; i < 4; i++){
      int row = r0 + lq * 4 + i;
      u32 vv = lgsa[(size_t)row * 128 + col];
      u16 hb = (u16)(vv >> 16);
      float sa = (float)(*(const _Float16*)&hb);
      float v = fast_tanh(sa + acc[nb][i] + bb);
      if (f32out) ((float*)outp)[(size_t)row * 128 + col] = v;
      else        ((u16*)  outp)[(size_t)row * 128 + col] = f2bf(v);
    }
  }
}

// ---------------- edge gather: half-channel split, 1 wave/node ----------------
__device__ __forceinline__ void acc_e(u32 g, float& s1, float& s2){
  float el = __uint_as_float(g << 16);
  float sv = __uint_as_float(g & 0xffff0000u);
  s1 += el;
  s2 = fmaf(el, sv, s2);
}

__global__ void __launch_bounds__(256) edge_kernel(const _Float16* __restrict__ eah,
    const u32* __restrict__ gat0, const u32* __restrict__ gat1,
    const int* __restrict__ row_start, const int* __restrict__ edge_dst,
    u32* __restrict__ lgsa){
  int blk = blockIdx.x;
  int xcd = blk & 7;
  int b = xcd >> 1, h = xcd & 1;
  int i = blk >> 3;                          // 0..2499
  int n = i * 4 + (int)(threadIdx.x >> 6);
  int node = b * NNODE + n;
  int c = threadIdx.x & 63;
  const u32* gh = (h ? gat1 : gat0) + (size_t)b * NNODE * 64;
  int e0 = __builtin_amdgcn_readfirstlane(row_start[b * (NNODE + 1) + n]);
  int e1 = __builtin_amdgcn_readfirstlane(row_start[b * (NNODE + 1) + n + 1]);
  const int* ed = edge_dst + (size_t)b * TWOE;

  float ea = (float)eah[(size_t)node * 128 + h * 64 + c];
  float s1 = 0.f, s2 = 0.f, t1 = 0.f, t2 = 0.f;
  int e = e0;
  for (; e + 8 <= e1; e += 8){
    int d0 = ed[e+0], d1 = ed[e+1], d2 = ed[e+2], d3 = ed[e+3];
    int d4 = ed[e+4], d5 = ed[e+5], d6 = ed[e+6], d7 = ed[e+7];
    u32 g0 = gh[(size_t)d0 * 64 + c];
    u32 g1 = gh[(size_t)d1 * 64 + c];
    u32 g2 = gh[(size_t)d2 * 64 + c];
    u32 g3 = gh[(size_t)d3 * 64 + c];
    u32 g4 = gh[(size_t)d4 * 64 + c];
    u32 g5 = gh[(size_t)d5 * 64 + c];
    u32 g6 = gh[(size_t)d6 * 64 + c];
    u32 g7 = gh[(size_t)d7 * 64 + c];
    acc_e(g0, s1, s2); acc_e(g1, t1, t2);
    acc_e(g2, s1, s2); acc_e(g3, t1, t2);
    acc_e(g4, s1, s2); acc_e(g5, t1, t2);
    acc_e(g6, s1, s2); acc_e(g7, t1, t2);
  }
  for (; e < e1; e++){
    u32 gg = gh[(size_t)ed[e] * 64 + c];
    acc_e(gg, s1, s2);
  }
  s1 += t1; s2 += t2;
  float inv = __builtin_amdgcn_rcpf(fmaf(ea, s1, 1.0f));
  float lg = ea * s2 * inv;
  u32 self = gh[(size_t)n * 64 + c];
  float s_self = __uint_as_float(self & 0xffff0000u);
  _Float16 hs = (_Float16)(s_self * inv);
  u32 pk = (u32)f2bf(lg) | ((u32)(*(const u16*)&hs) << 16);
  lgsa[(size_t)node * 128 + h * 64 + c] = pk;
}

// ---------------- host launcher ----------------------------------------------
extern "C" void kernel_launch(void* const* d_in, const int* in_sizes, int n_in,
                              void* d_out, int out_size, void* d_ws, size_t ws_size,
                              hipStream_t stream){
  (void)in_sizes; (void)n_in; (void)ws_size; (void)out_size;
  const void* objects = d_in[0];
  const void* Wo      = d_in[1];
  const void* Wa      = d_in[2];
  const void* Wla     = d_in[3];
  const void* attn_b  = d_in[4];
  const void* Wl      = d_in[5];
  const void* state_b = d_in[6];
  const int*  conn    = (const int*)d_in[7];

  char* base = (char*)d_ws;
  size_t off = 0;
  auto alloc = [&](size_t bytes) -> char* {
    char* p = base + off;
    off = (off + bytes + 255) & ~(size_t)255;
    return p;
  };
  int*      flag      = (int*)     alloc(256);
  u16*      Wt        = (u16*)     alloc((size_t)4 * 16384 * 2);
  float*    biasf     = (float*)   alloc(256 * 4);
  _Float16* eah       = (_Float16*)alloc((size_t)MROWS * 128 * 2);  // exp(aW) fp16
  u32*      gat0      = (u32*)     alloc((size_t)MROWS * 64 * 4);   // ch 0-63 {EL|S}
  u32*      gat1      = (u32*)     alloc((size_t)MROWS * 64 * 4);   // ch 64-127
  u32*      lgsa      = (u32*)     alloc((size_t)MROWS * 128 * 4);  // {lg bf16 | sa fp16}
  u16*      partial   = (u16*)     alloc((size_t)BATCH * NCHUNK * PADN * 2);
  int*      row_start = (int*)     alloc((size_t)BATCH * (NNODE + 1) * 4);
  int*      edge_dst  = (int*)     alloc((size_t)BATCH * TWOE * 4);
  int*      bsum      = (int*)     alloc(160 * 4);
  int*      boff      = (int*)     alloc(160 * 4);

  detect_dtype<<<1, 256, 0, stream>>>((const u32*)objects, flag);
  prep_weights<<<257, 256, 0, stream>>>(Wo, Wa, Wla, Wl, attn_b, state_b, flag, Wt, biasf);

  csr_hist<<<256, 256, 0, stream>>>(conn, partial);
  csr_colscan<<<160, 256, 0, stream>>>(partial, row_start, bsum);
  scanB<<<1, 256, 0, stream>>>(bsum, boff, row_start);
  scanC<<<160, 256, 0, stream>>>(row_start, boff);
  csr_fill<<<256, 256, 0, stream>>>(conn, partial, row_start, edge_dst);

  fused_init<<<MROWS / 32, 256, 0, stream>>>(objects, flag, Wt, biasf, eah, gat0, gat1);
  edge_kernel<<<MROWS / 2, 256, 0, stream>>>(eah, gat0, gat1, row_start, edge_dst, lgsa);
  fused_mid<<<MROWS / 32, 256, 0, stream>>>(lgsa, Wt, biasf, eah, gat0, gat1);
  edge_kernel<<<MROWS / 2, 256, 0, stream>>>(eah, gat0, gat1, row_start, edge_dst, lgsa);
  fused_mid<<<MROWS / 32, 256, 0, stream>>>(lgsa, Wt, biasf, eah, gat0, gat1);
  edge_kernel<<<MROWS / 2, 256, 0, stream>>>(eah, gat0, gat1, row_start, edge_dst, lgsa);
  final_out<<<MROWS / 32, 256, 0, stream>>>(lgsa, Wt, biasf, flag, d_out);
}